// Round 3
// baseline (2596.097 us; speedup 1.0000x reference)
//
#include <hip/hip_runtime.h>
#include <hip/hip_fp16.h>
#include <math.h>

#define BLK 128          // MLP / fused block
#define EBLK 256         // encode block

// ---------------- table f32 -> f16 conversion ----------------
__global__ __launch_bounds__(256) void cvt_table(const float4* __restrict__ src,
                                                 uint2* __restrict__ dst, int n4)
{
    int i = blockIdx.x * 256 + threadIdx.x;
    const int stride = gridDim.x * 256;
    for (; i < n4; i += stride) {
        const float4 v = src[i];
        const __half2 a = __floats2half2_rn(v.x, v.y);
        const __half2 b = __floats2half2_rn(v.z, v.w);
        uint2 o;
        o.x = *reinterpret_cast<const unsigned*>(&a);
        o.y = *reinterpret_cast<const unsigned*>(&b);
        dst[i] = o;
    }
}

// ---------------- hash-grid encode for one point ----------------
template<bool HALF_TABLE>
__device__ __forceinline__ void encode_point(float x, float y, float z,
                                             const float* __restrict__ tableF,
                                             const __half2* __restrict__ tableH,
                                             float (&emb)[32])
{
    constexpr int RES[16] = {32,38,46,55,67,80,97,116,140,168,203,244,294,353,425,512};
    constexpr int DN [16] = {1,1,1,1,1,1,1,1,1,1,1,1,0,0,0,0};
    constexpr int OFF[16] = {0,35937,95256,199079,374695,689127,1220568,2161760,
                             3763373,6566594,11393403,19883067,34589192,35113480,
                             35637768,36162056};
    constexpr unsigned NMASK = (1u << 19) - 1u;

    #pragma unroll
    for (int l = 0; l < 16; ++l) {
        const int res = RES[l];
        const float xl = x * (float)res, yl = y * (float)res, zl = z * (float)res;
        int cx = (int)floorf(xl); cx = cx < 0 ? 0 : (cx > res-1 ? res-1 : cx);
        int cy = (int)floorf(yl); cy = cy < 0 ? 0 : (cy > res-1 ? res-1 : cy);
        int cz = (int)floorf(zl); cz = cz < 0 ? 0 : (cz > res-1 ? res-1 : cz);
        const float wx = xl - (float)cx, wy = yl - (float)cy, wz = zl - (float)cz;

        int idx[8];
        #pragma unroll
        for (int c = 0; c < 8; ++c) {
            const int dx = (c >> 2) & 1, dy = (c >> 1) & 1, dz = c & 1;
            if (DN[l]) {
                idx[c] = (cx + dx) + (cy + dy) * (res + 1) + (cz + dz) * (res + 1) * (res + 1);
            } else {
                const unsigned ux = (unsigned)(cx + dx);
                const unsigned uy = (unsigned)(cy + dy);
                const unsigned uz = (unsigned)(cz + dz);
                const unsigned hh = ux ^ (uy * 2654435761u) ^ (uz * 805459861u);
                idx[c] = (int)(hh & NMASK);
            }
        }

        float2 v[8];
        if (HALF_TABLE) {
            #pragma unroll
            for (int c = 0; c < 8; ++c) v[c] = __half22float2(tableH[OFF[l] + idx[c]]);
        } else {
            #pragma unroll
            for (int c = 0; c < 8; ++c)
                v[c] = *reinterpret_cast<const float2*>(tableF + (size_t)2 * (size_t)(OFF[l] + idx[c]));
        }

        float e0 = 0.f, e1 = 0.f;
        #pragma unroll
        for (int c = 0; c < 8; ++c) {
            const int dx = (c >> 2) & 1, dy = (c >> 1) & 1, dz = c & 1;
            const float w = (dx ? wx : 1.f - wx) * (dy ? wy : 1.f - wy) * (dz ? wz : 1.f - wz);
            e0 = fmaf(v[c].x, w, e0);
            e1 = fmaf(v[c].y, w, e1);
        }
        emb[2*l+0] = e0;
        emb[2*l+1] = e1;
    }
}

// ---------------- encode kernel: gathers only, high occupancy ----------------
template<bool HALF_TABLE>
__global__ __launch_bounds__(EBLK, 7) void ngp_encode(
    const float* __restrict__ coords,
    const float* __restrict__ tableF,
    const __half2* __restrict__ tableH,
    uint4* __restrict__ emb_out,   // [N][4] uint4 = 32 fp16 per point
    int N)
{
    const int gi = blockIdx.x * EBLK + threadIdx.x;
    if (gi >= N) return;

    const float x = coords[3*gi+0];
    const float y = coords[3*gi+1];
    const float z = coords[3*gi+2];

    float emb[32];
    encode_point<HALF_TABLE>(x, y, z, tableF, tableH, emb);

    unsigned packed[16];
    #pragma unroll
    for (int i = 0; i < 16; ++i) {
        const __half2 h = __floats2half2_rn(emb[2*i+0], emb[2*i+1]);
        packed[i] = *reinterpret_cast<const unsigned*>(&h);
    }
    uint4* dst = emb_out + (size_t)gi * 4;
    #pragma unroll
    for (int k = 0; k < 4; ++k)
        dst[k] = make_uint4(packed[4*k+0], packed[4*k+1], packed[4*k+2], packed[4*k+3]);
}

// dense layer via 32-deep LDS staging column
template<int NIN, int NOUT, bool RELU>
__device__ __forceinline__ void dense(const float* __restrict__ W, const float* __restrict__ Bias,
                                      const float (&in)[NIN], float (&out)[NOUT], float* col)
{
    #pragma unroll
    for (int g = 0; g < NOUT; g += 32) {
        constexpr int GW = (NOUT < 32) ? NOUT : 32;
        #pragma unroll 4
        for (int j = g; j < g + GW; ++j) {
            float acc = Bias[j];
            #pragma unroll
            for (int i = 0; i < NIN; ++i) acc = fmaf(in[i], W[i * NOUT + j], acc);
            col[(j - g) * BLK] = RELU ? fmaxf(acc, 0.f) : acc;
        }
        #pragma unroll
        for (int i = g; i < g + GW; ++i) out[i] = col[(i - g) * BLK];
    }
}

// ---------------- MLP body for one point ----------------
__device__ __forceinline__ void mlp_point(
    const float (&emb)[32], float dx0, float dy0, float dz0,
    const float* __restrict__ fw1, const float* __restrict__ fb1,
    const float* __restrict__ fw2, const float* __restrict__ fb2,
    const float* __restrict__ fw3, const float* __restrict__ fb3,
    const float* __restrict__ rw1, const float* __restrict__ rb1,
    const float* __restrict__ rw2, const float* __restrict__ rb2,
    const float* __restrict__ rw3, const float* __restrict__ rb3,
    const float* __restrict__ rw4, const float* __restrict__ rb4,
    float* col, float4& outv)
{
    float A[64], B[64];
    dense<32, 64, true>(fw1, fb1, emb, A, col);
    dense<64, 64, true>(fw2, fb2, A,   B, col);

    float feat16[16];
    dense<64, 16, false>(fw3, fb3, B, feat16, col);
    const float sigma = expf(feat16[0]);

    float f[31];
    #pragma unroll
    for (int i = 0; i < 16; ++i) f[i] = feat16[i];
    f[16] = dx0; f[17] = dy0; f[18] = dz0;
    {
        float s, c;
        sincosf(dx0,      &s, &c); f[19] = s; f[25] = c;
        sincosf(2.f*dx0,  &s, &c); f[20] = s; f[26] = c;
        sincosf(dy0,      &s, &c); f[21] = s; f[27] = c;
        sincosf(2.f*dy0,  &s, &c); f[22] = s; f[28] = c;
        sincosf(dz0,      &s, &c); f[23] = s; f[29] = c;
        sincosf(2.f*dz0,  &s, &c); f[24] = s; f[30] = c;
    }

    dense<31, 64, true>(rw1, rb1, f, A, col);
    dense<64, 64, true>(rw2, rb2, A, B, col);
    dense<64, 64, true>(rw3, rb3, B, A, col);

    float o0 = rb4[0], o1 = rb4[1], o2 = rb4[2];
    #pragma unroll
    for (int i = 0; i < 64; ++i) {
        o0 = fmaf(A[i], rw4[i*3 + 0], o0);
        o1 = fmaf(A[i], rw4[i*3 + 1], o1);
        o2 = fmaf(A[i], rw4[i*3 + 2], o2);
    }
    o0 = 1.f / (1.f + expf(-o0));
    o1 = 1.f / (1.f + expf(-o1));
    o2 = 1.f / (1.f + expf(-o2));
    outv = make_float4(o0, o1, o2, sigma);
}

// ---------------- MLP kernel: reads packed fp16 emb ----------------
__global__ __launch_bounds__(BLK) void ngp_mlp(
    const uint4* __restrict__ emb_in,
    const float* __restrict__ dirs,
    const float* __restrict__ fw1, const float* __restrict__ fb1,
    const float* __restrict__ fw2, const float* __restrict__ fb2,
    const float* __restrict__ fw3, const float* __restrict__ fb3,
    const float* __restrict__ rw1, const float* __restrict__ rb1,
    const float* __restrict__ rw2, const float* __restrict__ rb2,
    const float* __restrict__ rw3, const float* __restrict__ rb3,
    const float* __restrict__ rw4, const float* __restrict__ rb4,
    float* __restrict__ out, int N)
{
    __shared__ float sbuf[32 * BLK];
    const int tid = threadIdx.x;
    const int gi  = blockIdx.x * BLK + tid;
    if (gi >= N) return;

    float emb[32];
    {
        const uint4* src = emb_in + (size_t)gi * 4;
        #pragma unroll
        for (int k = 0; k < 4; ++k) {
            const uint4 u = src[k];
            const unsigned w[4] = {u.x, u.y, u.z, u.w};
            #pragma unroll
            for (int q = 0; q < 4; ++q) {
                const __half2 h = *reinterpret_cast<const __half2*>(&w[q]);
                const float2 fv = __half22float2(h);
                emb[8*k + 2*q + 0] = fv.x;
                emb[8*k + 2*q + 1] = fv.y;
            }
        }
    }

    float4 ov;
    mlp_point(emb, dirs[3*gi+0], dirs[3*gi+1], dirs[3*gi+2],
              fw1, fb1, fw2, fb2, fw3, fb3,
              rw1, rb1, rw2, rb2, rw3, rb3, rw4, rb4,
              sbuf + tid, ov);
    reinterpret_cast<float4*>(out)[gi] = ov;
}

// ---------------- fused fallback (ws too small) ----------------
template<bool HALF_TABLE>
__global__ __launch_bounds__(BLK) void ngp_fused(
    const float* __restrict__ coords,
    const float* __restrict__ dirs,
    const float* __restrict__ tableF,
    const __half2* __restrict__ tableH,
    const float* __restrict__ fw1, const float* __restrict__ fb1,
    const float* __restrict__ fw2, const float* __restrict__ fb2,
    const float* __restrict__ fw3, const float* __restrict__ fb3,
    const float* __restrict__ rw1, const float* __restrict__ rb1,
    const float* __restrict__ rw2, const float* __restrict__ rb2,
    const float* __restrict__ rw3, const float* __restrict__ rb3,
    const float* __restrict__ rw4, const float* __restrict__ rb4,
    float* __restrict__ out, int N)
{
    __shared__ float sbuf[32 * BLK];
    const int tid = threadIdx.x;
    const int gi  = blockIdx.x * BLK + tid;
    if (gi >= N) return;

    float emb[32];
    encode_point<HALF_TABLE>(coords[3*gi+0], coords[3*gi+1], coords[3*gi+2],
                             tableF, tableH, emb);
    float4 ov;
    mlp_point(emb, dirs[3*gi+0], dirs[3*gi+1], dirs[3*gi+2],
              fw1, fb1, fw2, fb2, fw3, fb3,
              rw1, rb1, rw2, rb2, rw3, rb3, rw4, rb4,
              sbuf + tid, ov);
    reinterpret_cast<float4*>(out)[gi] = ov;
}

extern "C" void kernel_launch(void* const* d_in, const int* in_sizes, int n_in,
                              void* d_out, int out_size, void* d_ws, size_t ws_size,
                              hipStream_t stream)
{
    const float* coords = (const float*)d_in[0];
    const float* dirs   = (const float*)d_in[1];
    const float* table  = (const float*)d_in[2];
    const float* fw1 = (const float*)d_in[3];
    const float* fb1 = (const float*)d_in[4];
    const float* fw2 = (const float*)d_in[5];
    const float* fb2 = (const float*)d_in[6];
    const float* fw3 = (const float*)d_in[7];
    const float* fb3 = (const float*)d_in[8];
    const float* rw1 = (const float*)d_in[9];
    const float* rb1 = (const float*)d_in[10];
    const float* rw2 = (const float*)d_in[11];
    const float* rb2 = (const float*)d_in[12];
    const float* rw3 = (const float*)d_in[13];
    const float* rb3 = (const float*)d_in[14];
    const float* rw4 = (const float*)d_in[15];
    const float* rb4 = (const float*)d_in[16];

    const int N = in_sizes[0] / 3;

    const int table_floats = in_sizes[2];
    const size_t half_bytes = (size_t)table_floats * 2;              // fp16 table
    const size_t half_al    = (half_bytes + 255) & ~(size_t)255;
    const size_t emb_bytes  = (size_t)N * 32 * 2;                    // fp16 emb

    if (ws_size >= half_al + emb_bytes) {
        // ---- split path ----
        __half2* tableH = (__half2*)d_ws;
        uint4*   embws  = (uint4*)((char*)d_ws + half_al);
        hipLaunchKernelGGL(cvt_table, dim3(2048), dim3(256), 0, stream,
                           (const float4*)table, (uint2*)d_ws, table_floats / 4);
        hipLaunchKernelGGL((ngp_encode<true>), dim3((N + EBLK - 1) / EBLK), dim3(EBLK), 0, stream,
                           coords, table, tableH, embws, N);
        hipLaunchKernelGGL(ngp_mlp, dim3((N + BLK - 1) / BLK), dim3(BLK), 0, stream,
                           embws, dirs,
                           fw1, fb1, fw2, fb2, fw3, fb3,
                           rw1, rb1, rw2, rb2, rw3, rb3, rw4, rb4,
                           (float*)d_out, N);
    } else if (ws_size >= half_bytes) {
        __half2* tableH = (__half2*)d_ws;
        hipLaunchKernelGGL(cvt_table, dim3(2048), dim3(256), 0, stream,
                           (const float4*)table, (uint2*)d_ws, table_floats / 4);
        hipLaunchKernelGGL((ngp_fused<true>), dim3((N + BLK - 1) / BLK), dim3(BLK), 0, stream,
                           coords, dirs, table, tableH,
                           fw1, fb1, fw2, fb2, fw3, fb3,
                           rw1, rb1, rw2, rb2, rw3, rb3, rw4, rb4,
                           (float*)d_out, N);
    } else {
        hipLaunchKernelGGL((ngp_fused<false>), dim3((N + BLK - 1) / BLK), dim3(BLK), 0, stream,
                           coords, dirs, table, (const __half2*)nullptr,
                           fw1, fb1, fw2, fb2, fw3, fb3,
                           rw1, rb1, rw2, rb2, rw3, rb3, rw4, rb4,
                           (float*)d_out, N);
    }
}

// Round 4
// 1913.261 us; speedup vs baseline: 1.3569x; 1.3569x over previous
//
#include <hip/hip_runtime.h>
#include <hip/hip_fp16.h>
#include <math.h>

#define BLK 128          // MLP / fused block
#define EBLK 256         // encode / utility block
#define NBINS (1 << 18)  // 6 bits per axis, Morton

// ---------------- Morton key ----------------
__device__ __forceinline__ unsigned mexp(unsigned v) {
    v &= 0x3FF;
    v = (v | (v << 16)) & 0x030000FF;
    v = (v | (v << 8))  & 0x0300F00F;
    v = (v | (v << 4))  & 0x030C30C3;
    v = (v | (v << 2))  & 0x09249249;
    return v;
}
__device__ __forceinline__ unsigned morton_key(float x, float y, float z) {
    int bx = (int)(x * 64.f); bx = bx < 0 ? 0 : (bx > 63 ? 63 : bx);
    int by = (int)(y * 64.f); by = by < 0 ? 0 : (by > 63 ? 63 : by);
    int bz = (int)(z * 64.f); bz = bz < 0 ? 0 : (bz > 63 ? 63 : bz);
    return (mexp((unsigned)bx) << 2) | (mexp((unsigned)by) << 1) | mexp((unsigned)bz);
}

// ---------------- table f32 -> f16 ----------------
__global__ __launch_bounds__(256) void cvt_table(const float* __restrict__ srcF,
                                                 __half* __restrict__ dstH, int nfloats)
{
    const int n4 = nfloats >> 2;
    const float4* src = (const float4*)srcF;
    uint2* dst = (uint2*)dstH;
    int i = blockIdx.x * 256 + threadIdx.x;
    const int stride = gridDim.x * 256;
    for (; i < n4; i += stride) {
        const float4 v = src[i];
        const __half2 a = __floats2half2_rn(v.x, v.y);
        const __half2 b = __floats2half2_rn(v.z, v.w);
        uint2 o;
        o.x = *reinterpret_cast<const unsigned*>(&a);
        o.y = *reinterpret_cast<const unsigned*>(&b);
        dst[i] = o;
    }
    for (int j = (n4 << 2) + blockIdx.x * 256 + threadIdx.x; j < nfloats; j += stride)
        dstH[j] = __float2half(srcF[j]);
}

// ---------------- sort: histogram ----------------
__global__ __launch_bounds__(256) void hist_build(const float* __restrict__ coords,
                                                  unsigned* __restrict__ hist, int N)
{
    const int i = blockIdx.x * 256 + threadIdx.x;
    if (i >= N) return;
    const unsigned key = morton_key(coords[3*i+0], coords[3*i+1], coords[3*i+2]);
    atomicAdd(&hist[key], 1u);
}

// ---------------- sort: hierarchical exclusive scan ----------------
__global__ __launch_bounds__(256) void scan1(unsigned* __restrict__ hist, unsigned* __restrict__ bsum)
{
    __shared__ unsigned sa[256], sb[256];
    const int t = threadIdx.x;
    const unsigned base = blockIdx.x * 1024u + (unsigned)t * 4u;
    const unsigned v0 = hist[base+0], v1 = hist[base+1], v2 = hist[base+2], v3 = hist[base+3];
    const unsigned sum = v0 + v1 + v2 + v3;
    sa[t] = sum; __syncthreads();
    unsigned* src = sa; unsigned* dst = sb;
    for (int off = 1; off < 256; off <<= 1) {
        dst[t] = src[t] + (t >= off ? src[t - off] : 0u);
        __syncthreads();
        unsigned* tmp = src; src = dst; dst = tmp;
    }
    const unsigned incl = src[t];
    unsigned run = incl - sum;
    hist[base+0] = run; run += v0;
    hist[base+1] = run; run += v1;
    hist[base+2] = run; run += v2;
    hist[base+3] = run;
    if (t == 255) bsum[blockIdx.x] = incl;
}

__global__ __launch_bounds__(256) void scan2(unsigned* __restrict__ bsum)
{
    __shared__ unsigned sa[256], sb[256];
    const int t = threadIdx.x;
    const unsigned v = bsum[t];
    sa[t] = v; __syncthreads();
    unsigned* src = sa; unsigned* dst = sb;
    for (int off = 1; off < 256; off <<= 1) {
        dst[t] = src[t] + (t >= off ? src[t - off] : 0u);
        __syncthreads();
        unsigned* tmp = src; src = dst; dst = tmp;
    }
    bsum[t] = src[t] - v;
}

__global__ __launch_bounds__(256) void scan3(const unsigned* __restrict__ hist,
                                             const unsigned* __restrict__ bsum,
                                             unsigned* __restrict__ cursor)
{
    const int i = blockIdx.x * 256 + threadIdx.x;
    cursor[i] = hist[i] + bsum[i >> 10];
}

// ---------------- sort: scatter points into bins ----------------
__global__ __launch_bounds__(256) void scatter_pts(const float* __restrict__ coords,
                                                   const float* __restrict__ dirs,
                                                   unsigned* __restrict__ cursor,
                                                   float4* __restrict__ cS,
                                                   float4* __restrict__ dS, int N)
{
    const int i = blockIdx.x * 256 + threadIdx.x;
    if (i >= N) return;
    const float x = coords[3*i+0], y = coords[3*i+1], z = coords[3*i+2];
    const unsigned key = morton_key(x, y, z);
    const unsigned slot = atomicAdd(&cursor[key], 1u);
    cS[slot] = make_float4(x, y, z, __uint_as_float((unsigned)i));
    dS[slot] = make_float4(dirs[3*i+0], dirs[3*i+1], dirs[3*i+2], __uint_as_float((unsigned)i));
}

// ---------------- hash-grid encode for one point ----------------
template<bool HALF_TABLE>
__device__ __forceinline__ void encode_point(float x, float y, float z,
                                             const float* __restrict__ tableF,
                                             const __half2* __restrict__ tableH,
                                             float (&emb)[32])
{
    constexpr int RES[16] = {32,38,46,55,67,80,97,116,140,168,203,244,294,353,425,512};
    constexpr int DN [16] = {1,1,1,1,1,1,1,1,1,1,1,1,0,0,0,0};
    constexpr int OFF[16] = {0,35937,95256,199079,374695,689127,1220568,2161760,
                             3763373,6566594,11393403,19883067,34589192,35113480,
                             35637768,36162056};
    constexpr unsigned NMASK = (1u << 19) - 1u;

    #pragma unroll
    for (int l = 0; l < 16; ++l) {
        const int res = RES[l];
        const float xl = x * (float)res, yl = y * (float)res, zl = z * (float)res;
        int cx = (int)floorf(xl); cx = cx < 0 ? 0 : (cx > res-1 ? res-1 : cx);
        int cy = (int)floorf(yl); cy = cy < 0 ? 0 : (cy > res-1 ? res-1 : cy);
        int cz = (int)floorf(zl); cz = cz < 0 ? 0 : (cz > res-1 ? res-1 : cz);
        const float wx = xl - (float)cx, wy = yl - (float)cy, wz = zl - (float)cz;

        int idx[8];
        #pragma unroll
        for (int c = 0; c < 8; ++c) {
            const int dx = (c >> 2) & 1, dy = (c >> 1) & 1, dz = c & 1;
            if (DN[l]) {
                idx[c] = (cx + dx) + (cy + dy) * (res + 1) + (cz + dz) * (res + 1) * (res + 1);
            } else {
                const unsigned ux = (unsigned)(cx + dx);
                const unsigned uy = (unsigned)(cy + dy);
                const unsigned uz = (unsigned)(cz + dz);
                const unsigned hh = ux ^ (uy * 2654435761u) ^ (uz * 805459861u);
                idx[c] = (int)(hh & NMASK);
            }
        }

        float2 v[8];
        if (HALF_TABLE) {
            #pragma unroll
            for (int c = 0; c < 8; ++c) v[c] = __half22float2(tableH[OFF[l] + idx[c]]);
        } else {
            #pragma unroll
            for (int c = 0; c < 8; ++c)
                v[c] = *reinterpret_cast<const float2*>(tableF + (size_t)2 * (size_t)(OFF[l] + idx[c]));
        }

        float e0 = 0.f, e1 = 0.f;
        #pragma unroll
        for (int c = 0; c < 8; ++c) {
            const int dx = (c >> 2) & 1, dy = (c >> 1) & 1, dz = c & 1;
            const float w = (dx ? wx : 1.f - wx) * (dy ? wy : 1.f - wy) * (dz ? wz : 1.f - wz);
            e0 = fmaf(v[c].x, w, e0);
            e1 = fmaf(v[c].y, w, e1);
        }
        emb[2*l+0] = e0;
        emb[2*l+1] = e1;
    }
}

// ---------------- encode kernel (sorted input) ----------------
template<bool HALF_TABLE>
__global__ __launch_bounds__(EBLK, 7) void ngp_encode(
    const float4* __restrict__ cS,
    const float* __restrict__ tableF,
    const __half2* __restrict__ tableH,
    uint4* __restrict__ emb_out, int N)
{
    const int gi = blockIdx.x * EBLK + threadIdx.x;
    if (gi >= N) return;

    const float4 c = cS[gi];
    float emb[32];
    encode_point<HALF_TABLE>(c.x, c.y, c.z, tableF, tableH, emb);

    unsigned packed[16];
    #pragma unroll
    for (int i = 0; i < 16; ++i) {
        const __half2 h = __floats2half2_rn(emb[2*i+0], emb[2*i+1]);
        packed[i] = *reinterpret_cast<const unsigned*>(&h);
    }
    uint4* dst = emb_out + (size_t)gi * 4;
    #pragma unroll
    for (int k = 0; k < 4; ++k)
        dst[k] = make_uint4(packed[4*k+0], packed[4*k+1], packed[4*k+2], packed[4*k+3]);
}

// ---------------- dense layer: LDS-column inputs, register accumulators ----------------
template<int NIN, int NOUT, bool RELU>
__device__ __forceinline__ void dense_l(const float* __restrict__ W, const float* __restrict__ Bias,
                                        const float* __restrict__ col, float (&out)[NOUT])
{
    #pragma unroll
    for (int j = 0; j < NOUT; ++j) out[j] = Bias[j];
    #pragma unroll 4
    for (int i = 0; i < NIN; ++i) {
        const float a = col[i * BLK];
        const float* Wr = W + i * NOUT;
        #pragma unroll
        for (int j = 0; j < NOUT; ++j) out[j] = fmaf(a, Wr[j], out[j]);
    }
    if (RELU) {
        #pragma unroll
        for (int j = 0; j < NOUT; ++j) out[j] = fmaxf(out[j], 0.f);
    }
}

// ---------------- MLP body; assumes col[0..31] holds emb ----------------
__device__ __forceinline__ float4 mlp_lds(float* col, float dx0, float dy0, float dz0,
    const float* __restrict__ fw1, const float* __restrict__ fb1,
    const float* __restrict__ fw2, const float* __restrict__ fb2,
    const float* __restrict__ fw3, const float* __restrict__ fb3,
    const float* __restrict__ rw1, const float* __restrict__ rb1,
    const float* __restrict__ rw2, const float* __restrict__ rb2,
    const float* __restrict__ rw3, const float* __restrict__ rb3,
    const float* __restrict__ rw4, const float* __restrict__ rb4)
{
    float h[64];
    dense_l<32, 64, true>(fw1, fb1, col, h);
    #pragma unroll
    for (int j = 0; j < 64; ++j) col[j * BLK] = h[j];

    dense_l<64, 64, true>(fw2, fb2, col, h);
    #pragma unroll
    for (int j = 0; j < 64; ++j) col[j * BLK] = h[j];

    float feat16[16];
    dense_l<64, 16, false>(fw3, fb3, col, feat16);
    const float sigma = expf(feat16[0]);

    // stage f = [feat16, pe] in col
    #pragma unroll
    for (int j = 0; j < 16; ++j) col[j * BLK] = feat16[j];
    col[16 * BLK] = dx0; col[17 * BLK] = dy0; col[18 * BLK] = dz0;
    {
        float s, c;
        sincosf(dx0,     &s, &c); col[19 * BLK] = s; col[25 * BLK] = c;
        sincosf(2.f*dx0, &s, &c); col[20 * BLK] = s; col[26 * BLK] = c;
        sincosf(dy0,     &s, &c); col[21 * BLK] = s; col[27 * BLK] = c;
        sincosf(2.f*dy0, &s, &c); col[22 * BLK] = s; col[28 * BLK] = c;
        sincosf(dz0,     &s, &c); col[23 * BLK] = s; col[29 * BLK] = c;
        sincosf(2.f*dz0, &s, &c); col[24 * BLK] = s; col[30 * BLK] = c;
    }

    dense_l<31, 64, true>(rw1, rb1, col, h);
    #pragma unroll
    for (int j = 0; j < 64; ++j) col[j * BLK] = h[j];

    dense_l<64, 64, true>(rw2, rb2, col, h);
    #pragma unroll
    for (int j = 0; j < 64; ++j) col[j * BLK] = h[j];

    dense_l<64, 64, true>(rw3, rb3, col, h);
    #pragma unroll
    for (int j = 0; j < 64; ++j) col[j * BLK] = h[j];

    float o0 = rb4[0], o1 = rb4[1], o2 = rb4[2];
    #pragma unroll 4
    for (int i = 0; i < 64; ++i) {
        const float a = col[i * BLK];
        o0 = fmaf(a, rw4[i*3 + 0], o0);
        o1 = fmaf(a, rw4[i*3 + 1], o1);
        o2 = fmaf(a, rw4[i*3 + 2], o2);
    }
    o0 = 1.f / (1.f + expf(-o0));
    o1 = 1.f / (1.f + expf(-o1));
    o2 = 1.f / (1.f + expf(-o2));
    return make_float4(o0, o1, o2, sigma);
}

// ---------------- MLP kernel (sorted): seq emb, seq dirs, scatter out ----------------
__global__ __launch_bounds__(BLK) void ngp_mlp(
    const uint4* __restrict__ emb_in,
    const float4* __restrict__ dS,
    const float* __restrict__ fw1, const float* __restrict__ fb1,
    const float* __restrict__ fw2, const float* __restrict__ fb2,
    const float* __restrict__ fw3, const float* __restrict__ fb3,
    const float* __restrict__ rw1, const float* __restrict__ rb1,
    const float* __restrict__ rw2, const float* __restrict__ rb2,
    const float* __restrict__ rw3, const float* __restrict__ rb3,
    const float* __restrict__ rw4, const float* __restrict__ rb4,
    float* __restrict__ out, int N)
{
    __shared__ float sbuf[64 * BLK];   // 32 KB
    const int tid = threadIdx.x;
    const int gi  = blockIdx.x * BLK + tid;
    if (gi >= N) return;

    float* col = sbuf + tid;
    {
        const uint4* src = emb_in + (size_t)gi * 4;
        #pragma unroll
        for (int k = 0; k < 4; ++k) {
            const uint4 u = src[k];
            const unsigned w[4] = {u.x, u.y, u.z, u.w};
            #pragma unroll
            for (int q = 0; q < 4; ++q) {
                const __half2 hh = *reinterpret_cast<const __half2*>(&w[q]);
                const float2 fv = __half22float2(hh);
                col[(8*k + 2*q + 0) * BLK] = fv.x;
                col[(8*k + 2*q + 1) * BLK] = fv.y;
            }
        }
    }

    const float4 d4 = dS[gi];
    const float4 ov = mlp_lds(col, d4.x, d4.y, d4.z,
                              fw1, fb1, fw2, fb2, fw3, fb3,
                              rw1, rb1, rw2, rb2, rw3, rb3, rw4, rb4);
    const unsigned p = __float_as_uint(d4.w);
    reinterpret_cast<float4*>(out)[p] = ov;
}

// ---------------- fused fallback (small ws) ----------------
template<bool HALF_TABLE>
__global__ __launch_bounds__(BLK) void ngp_fused(
    const float* __restrict__ coords,
    const float* __restrict__ dirs,
    const float* __restrict__ tableF,
    const __half2* __restrict__ tableH,
    const float* __restrict__ fw1, const float* __restrict__ fb1,
    const float* __restrict__ fw2, const float* __restrict__ fb2,
    const float* __restrict__ fw3, const float* __restrict__ fb3,
    const float* __restrict__ rw1, const float* __restrict__ rb1,
    const float* __restrict__ rw2, const float* __restrict__ rb2,
    const float* __restrict__ rw3, const float* __restrict__ rb3,
    const float* __restrict__ rw4, const float* __restrict__ rb4,
    float* __restrict__ out, int N)
{
    __shared__ float sbuf[64 * BLK];
    const int tid = threadIdx.x;
    const int gi  = blockIdx.x * BLK + tid;
    if (gi >= N) return;

    float emb[32];
    encode_point<HALF_TABLE>(coords[3*gi+0], coords[3*gi+1], coords[3*gi+2],
                             tableF, tableH, emb);
    float* col = sbuf + tid;
    #pragma unroll
    for (int j = 0; j < 32; ++j) col[j * BLK] = emb[j];

    const float4 ov = mlp_lds(col, dirs[3*gi+0], dirs[3*gi+1], dirs[3*gi+2],
                              fw1, fb1, fw2, fb2, fw3, fb3,
                              rw1, rb1, rw2, rb2, rw3, rb3, rw4, rb4);
    reinterpret_cast<float4*>(out)[gi] = ov;
}

extern "C" void kernel_launch(void* const* d_in, const int* in_sizes, int n_in,
                              void* d_out, int out_size, void* d_ws, size_t ws_size,
                              hipStream_t stream)
{
    const float* coords = (const float*)d_in[0];
    const float* dirs   = (const float*)d_in[1];
    const float* table  = (const float*)d_in[2];
    const float* fw1 = (const float*)d_in[3];
    const float* fb1 = (const float*)d_in[4];
    const float* fw2 = (const float*)d_in[5];
    const float* fb2 = (const float*)d_in[6];
    const float* fw3 = (const float*)d_in[7];
    const float* fb3 = (const float*)d_in[8];
    const float* rw1 = (const float*)d_in[9];
    const float* rb1 = (const float*)d_in[10];
    const float* rw2 = (const float*)d_in[11];
    const float* rb2 = (const float*)d_in[12];
    const float* rw3 = (const float*)d_in[13];
    const float* rb3 = (const float*)d_in[14];
    const float* rw4 = (const float*)d_in[15];
    const float* rb4 = (const float*)d_in[16];

    const int N = in_sizes[0] / 3;
    const int table_floats = in_sizes[2];

    // ws layout
    size_t pos = 0;
    auto take = [&](size_t bytes) { size_t p = pos; pos = (pos + bytes + 255) & ~(size_t)255; return p; };
    const size_t o_tableH = take((size_t)table_floats * 2);
    const size_t o_emb    = take((size_t)N * 64);
    const size_t o_cS     = take((size_t)N * 16);
    const size_t o_dS     = take((size_t)N * 16);
    const size_t o_hist   = take((size_t)NBINS * 4);
    const size_t o_cursor = take((size_t)NBINS * 4);
    const size_t o_bsum   = take(256 * 4);
    const size_t need_full = pos;
    const size_t need_half = (size_t)table_floats * 2;

    char* ws = (char*)d_ws;

    if (ws_size >= need_full) {
        __half*   tableH = (__half*)(ws + o_tableH);
        uint4*    embws  = (uint4*)(ws + o_emb);
        float4*   cS     = (float4*)(ws + o_cS);
        float4*   dS     = (float4*)(ws + o_dS);
        unsigned* hist   = (unsigned*)(ws + o_hist);
        unsigned* cursor = (unsigned*)(ws + o_cursor);
        unsigned* bsum   = (unsigned*)(ws + o_bsum);

        hipLaunchKernelGGL(cvt_table, dim3(2048), dim3(256), 0, stream,
                           table, tableH, table_floats);
        hipMemsetAsync(hist, 0, (size_t)NBINS * 4, stream);
        hipLaunchKernelGGL(hist_build, dim3((N + 255) / 256), dim3(256), 0, stream,
                           coords, hist, N);
        hipLaunchKernelGGL(scan1, dim3(NBINS / 1024), dim3(256), 0, stream, hist, bsum);
        hipLaunchKernelGGL(scan2, dim3(1), dim3(256), 0, stream, bsum);
        hipLaunchKernelGGL(scan3, dim3(NBINS / 256), dim3(256), 0, stream, hist, bsum, cursor);
        hipLaunchKernelGGL(scatter_pts, dim3((N + 255) / 256), dim3(256), 0, stream,
                           coords, dirs, cursor, cS, dS, N);
        hipLaunchKernelGGL((ngp_encode<true>), dim3((N + EBLK - 1) / EBLK), dim3(EBLK), 0, stream,
                           cS, table, (const __half2*)tableH, embws, N);
        hipLaunchKernelGGL(ngp_mlp, dim3((N + BLK - 1) / BLK), dim3(BLK), 0, stream,
                           embws, dS,
                           fw1, fb1, fw2, fb2, fw3, fb3,
                           rw1, rb1, rw2, rb2, rw3, rb3, rw4, rb4,
                           (float*)d_out, N);
    } else if (ws_size >= need_half) {
        __half* tableH = (__half*)ws;
        hipLaunchKernelGGL(cvt_table, dim3(2048), dim3(256), 0, stream,
                           table, tableH, table_floats);
        hipLaunchKernelGGL((ngp_fused<true>), dim3((N + BLK - 1) / BLK), dim3(BLK), 0, stream,
                           coords, dirs, table, (const __half2*)tableH,
                           fw1, fb1, fw2, fb2, fw3, fb3,
                           rw1, rb1, rw2, rb2, rw3, rb3, rw4, rb4,
                           (float*)d_out, N);
    } else {
        hipLaunchKernelGGL((ngp_fused<false>), dim3((N + BLK - 1) / BLK), dim3(BLK), 0, stream,
                           coords, dirs, table, (const __half2*)nullptr,
                           fw1, fb1, fw2, fb2, fw3, fb3,
                           rw1, rb1, rw2, rb2, rw3, rb3, rw4, rb4,
                           (float*)d_out, N);
    }
}

// Round 5
// 1021.669 us; speedup vs baseline: 2.5410x; 1.8727x over previous
//
#include <hip/hip_runtime.h>
#include <hip/hip_fp16.h>
#include <math.h>

#define BLK 128          // fused-fallback block
#define EBLK 256         // encode / utility block
#define NBINS (1 << 18)  // 6 bits per axis, Morton

typedef __attribute__((ext_vector_type(8))) _Float16 half8;
typedef __attribute__((ext_vector_type(4))) float f32x4;

// frag offsets in f16 elements: L1,L2,L3,R1,R2,R3,R4
#define FO_L1 0
#define FO_L2 2048
#define FO_L3 6144
#define FO_R1 7168
#define FO_R2 9216
#define FO_R3 13312
#define FO_R4 17408
#define FRAG_TOTAL 18432

// ---------------- Morton key ----------------
__device__ __forceinline__ unsigned mexp(unsigned v) {
    v &= 0x3FF;
    v = (v | (v << 16)) & 0x030000FF;
    v = (v | (v << 8))  & 0x0300F00F;
    v = (v | (v << 4))  & 0x030C30C3;
    v = (v | (v << 2))  & 0x09249249;
    return v;
}
__device__ __forceinline__ unsigned morton_key(float x, float y, float z) {
    int bx = (int)(x * 64.f); bx = bx < 0 ? 0 : (bx > 63 ? 63 : bx);
    int by = (int)(y * 64.f); by = by < 0 ? 0 : (by > 63 ? 63 : by);
    int bz = (int)(z * 64.f); bz = bz < 0 ? 0 : (bz > 63 ? 63 : bz);
    return (mexp((unsigned)bx) << 2) | (mexp((unsigned)by) << 1) | mexp((unsigned)bz);
}

// ---------------- table f32 -> f16 ----------------
__global__ __launch_bounds__(256) void cvt_table(const float* __restrict__ srcF,
                                                 __half* __restrict__ dstH, int nfloats)
{
    const int n4 = nfloats >> 2;
    const float4* src = (const float4*)srcF;
    uint2* dst = (uint2*)dstH;
    int i = blockIdx.x * 256 + threadIdx.x;
    const int stride = gridDim.x * 256;
    for (; i < n4; i += stride) {
        const float4 v = src[i];
        const __half2 a = __floats2half2_rn(v.x, v.y);
        const __half2 b = __floats2half2_rn(v.z, v.w);
        uint2 o;
        o.x = *reinterpret_cast<const unsigned*>(&a);
        o.y = *reinterpret_cast<const unsigned*>(&b);
        dst[i] = o;
    }
    for (int j = (n4 << 2) + blockIdx.x * 256 + threadIdx.x; j < nfloats; j += stride)
        dstH[j] = __float2half(srcF[j]);
}

// ---------------- weight fragment packing ----------------
__global__ __launch_bounds__(256) void prep_frags(
    const float* __restrict__ fw1, const float* __restrict__ fw2, const float* __restrict__ fw3,
    const float* __restrict__ rw1, const float* __restrict__ rw2, const float* __restrict__ rw3,
    const float* __restrict__ rw4, _Float16* __restrict__ frag)
{
    const int gid = blockIdx.x * 256 + threadIdx.x;
    if (gid >= FRAG_TOTAL) return;
    constexpr int offs[8] = {FO_L1, FO_L2, FO_L3, FO_R1, FO_R2, FO_R3, FO_R4, FRAG_TOTAL};
    constexpr int Ks[7]   = {32, 64, 64, 31, 64, 64, 64};
    constexpr int NO[7]   = {64, 64, 16, 64, 64, 64, 3};
    constexpr int NKs[7]  = {1, 2, 2, 1, 2, 2, 2};
    int layer = 0;
    #pragma unroll
    for (int i = 1; i < 7; ++i) if (gid >= offs[i]) layer = i;
    const float* W = fw1;
    if (layer == 1) W = fw2; else if (layer == 2) W = fw3;
    else if (layer == 3) W = rw1; else if (layer == 4) W = rw2;
    else if (layer == 5) W = rw3; else if (layer == 6) W = rw4;

    const int e = gid - offs[layer];
    const int nk = NKs[layer];
    const int blk = e >> 9, within = e & 511;
    const int t = blk / nk, ks = blk - t * nk;
    const int lane = within >> 3, i = within & 7;
    const int k = ks * 32 + (lane >> 4) * 8 + i;
    const int col = t * 16 + (lane & 15);
    float v = 0.f;
    if (k < Ks[layer] && col < NO[layer]) v = W[k * NO[layer] + col];
    frag[gid] = (_Float16)v;
}

// ---------------- sort: histogram ----------------
__global__ __launch_bounds__(256) void hist_build(const float* __restrict__ coords,
                                                  unsigned* __restrict__ hist, int N)
{
    const int i = blockIdx.x * 256 + threadIdx.x;
    if (i >= N) return;
    const unsigned key = morton_key(coords[3*i+0], coords[3*i+1], coords[3*i+2]);
    atomicAdd(&hist[key], 1u);
}

// ---------------- sort: hierarchical exclusive scan ----------------
__global__ __launch_bounds__(256) void scan1(unsigned* __restrict__ hist, unsigned* __restrict__ bsum)
{
    __shared__ unsigned sa[256], sb[256];
    const int t = threadIdx.x;
    const unsigned base = blockIdx.x * 1024u + (unsigned)t * 4u;
    const unsigned v0 = hist[base+0], v1 = hist[base+1], v2 = hist[base+2], v3 = hist[base+3];
    const unsigned sum = v0 + v1 + v2 + v3;
    sa[t] = sum; __syncthreads();
    unsigned* src = sa; unsigned* dst = sb;
    for (int off = 1; off < 256; off <<= 1) {
        dst[t] = src[t] + (t >= off ? src[t - off] : 0u);
        __syncthreads();
        unsigned* tmp = src; src = dst; dst = tmp;
    }
    const unsigned incl = src[t];
    unsigned run = incl - sum;
    hist[base+0] = run; run += v0;
    hist[base+1] = run; run += v1;
    hist[base+2] = run; run += v2;
    hist[base+3] = run;
    if (t == 255) bsum[blockIdx.x] = incl;
}

__global__ __launch_bounds__(256) void scan2(unsigned* __restrict__ bsum)
{
    __shared__ unsigned sa[256], sb[256];
    const int t = threadIdx.x;
    const unsigned v = bsum[t];
    sa[t] = v; __syncthreads();
    unsigned* src = sa; unsigned* dst = sb;
    for (int off = 1; off < 256; off <<= 1) {
        dst[t] = src[t] + (t >= off ? src[t - off] : 0u);
        __syncthreads();
        unsigned* tmp = src; src = dst; dst = tmp;
    }
    bsum[t] = src[t] - v;
}

__global__ __launch_bounds__(256) void scan3(const unsigned* __restrict__ hist,
                                             const unsigned* __restrict__ bsum,
                                             unsigned* __restrict__ cursor)
{
    const int i = blockIdx.x * 256 + threadIdx.x;
    cursor[i] = hist[i] + bsum[i >> 10];
}

// ---------------- sort: scatter points into bins ----------------
__global__ __launch_bounds__(256) void scatter_pts(const float* __restrict__ coords,
                                                   const float* __restrict__ dirs,
                                                   unsigned* __restrict__ cursor,
                                                   float4* __restrict__ cS,
                                                   float4* __restrict__ dS, int N)
{
    const int i = blockIdx.x * 256 + threadIdx.x;
    if (i >= N) return;
    const float x = coords[3*i+0], y = coords[3*i+1], z = coords[3*i+2];
    const unsigned key = morton_key(x, y, z);
    const unsigned slot = atomicAdd(&cursor[key], 1u);
    cS[slot] = make_float4(x, y, z, __uint_as_float((unsigned)i));
    dS[slot] = make_float4(dirs[3*i+0], dirs[3*i+1], dirs[3*i+2], __uint_as_float((unsigned)i));
}

// ---------------- hash-grid encode for one point ----------------
template<bool HALF_TABLE>
__device__ __forceinline__ void encode_point(float x, float y, float z,
                                             const float* __restrict__ tableF,
                                             const __half2* __restrict__ tableH,
                                             float (&emb)[32])
{
    constexpr int RES[16] = {32,38,46,55,67,80,97,116,140,168,203,244,294,353,425,512};
    constexpr int DN [16] = {1,1,1,1,1,1,1,1,1,1,1,1,0,0,0,0};
    constexpr int OFF[16] = {0,35937,95256,199079,374695,689127,1220568,2161760,
                             3763373,6566594,11393403,19883067,34589192,35113480,
                             35637768,36162056};
    constexpr unsigned NMASK = (1u << 19) - 1u;

    #pragma unroll
    for (int l = 0; l < 16; ++l) {
        const int res = RES[l];
        const float xl = x * (float)res, yl = y * (float)res, zl = z * (float)res;
        int cx = (int)floorf(xl); cx = cx < 0 ? 0 : (cx > res-1 ? res-1 : cx);
        int cy = (int)floorf(yl); cy = cy < 0 ? 0 : (cy > res-1 ? res-1 : cy);
        int cz = (int)floorf(zl); cz = cz < 0 ? 0 : (cz > res-1 ? res-1 : cz);
        const float wx = xl - (float)cx, wy = yl - (float)cy, wz = zl - (float)cz;

        int idx[8];
        #pragma unroll
        for (int c = 0; c < 8; ++c) {
            const int dx = (c >> 2) & 1, dy = (c >> 1) & 1, dz = c & 1;
            if (DN[l]) {
                idx[c] = (cx + dx) + (cy + dy) * (res + 1) + (cz + dz) * (res + 1) * (res + 1);
            } else {
                const unsigned ux = (unsigned)(cx + dx);
                const unsigned uy = (unsigned)(cy + dy);
                const unsigned uz = (unsigned)(cz + dz);
                const unsigned hh = ux ^ (uy * 2654435761u) ^ (uz * 805459861u);
                idx[c] = (int)(hh & NMASK);
            }
        }

        float2 v[8];
        if (HALF_TABLE) {
            #pragma unroll
            for (int c = 0; c < 8; ++c) v[c] = __half22float2(tableH[OFF[l] + idx[c]]);
        } else {
            #pragma unroll
            for (int c = 0; c < 8; ++c)
                v[c] = *reinterpret_cast<const float2*>(tableF + (size_t)2 * (size_t)(OFF[l] + idx[c]));
        }

        float e0 = 0.f, e1 = 0.f;
        #pragma unroll
        for (int c = 0; c < 8; ++c) {
            const int dx = (c >> 2) & 1, dy = (c >> 1) & 1, dz = c & 1;
            const float w = (dx ? wx : 1.f - wx) * (dy ? wy : 1.f - wy) * (dz ? wz : 1.f - wz);
            e0 = fmaf(v[c].x, w, e0);
            e1 = fmaf(v[c].y, w, e1);
        }
        emb[2*l+0] = e0;
        emb[2*l+1] = e1;
    }
}

// ---------------- encode kernel (sorted input) ----------------
template<bool HALF_TABLE>
__global__ __launch_bounds__(EBLK, 7) void ngp_encode(
    const float4* __restrict__ cS,
    const float* __restrict__ tableF,
    const __half2* __restrict__ tableH,
    uint4* __restrict__ emb_out, int N)
{
    const int gi = blockIdx.x * EBLK + threadIdx.x;
    if (gi >= N) return;

    const float4 c = cS[gi];
    float emb[32];
    encode_point<HALF_TABLE>(c.x, c.y, c.z, tableF, tableH, emb);

    unsigned packed[16];
    #pragma unroll
    for (int i = 0; i < 16; ++i) {
        const __half2 h = __floats2half2_rn(emb[2*i+0], emb[2*i+1]);
        packed[i] = *reinterpret_cast<const unsigned*>(&h);
    }
    uint4* dst = emb_out + (size_t)gi * 4;
    #pragma unroll
    for (int k = 0; k < 4; ++k)
        dst[k] = make_uint4(packed[4*k+0], packed[4*k+1], packed[4*k+2], packed[4*k+3]);
}

// ================= MFMA MLP =================
__device__ __forceinline__ half8 ldfrag(const _Float16* __restrict__ frags, int off, int l) {
    return *reinterpret_cast<const half8*>(frags + off + l * 8);
}
__device__ __forceinline__ int swz(int f, int p) {
    return ((((f >> 3) + p) & 7) << 3) | (f & 7);
}
__device__ __forceinline__ half8 loadA(const _Float16* T, int p, int kb) {
    return *reinterpret_cast<const half8*>(T + p * 64 + ((((kb >> 3) + p) & 7) << 3));
}

template<bool RELU>
__device__ __forceinline__ void storeD4(_Float16* T, const f32x4 (&acc)[4], int p16, int g) {
    #pragma unroll
    for (int t = 0; t < 4; ++t) {
        #pragma unroll
        for (int r = 0; r < 4; ++r) {
            float v = acc[t][r];
            if (RELU) v = fmaxf(v, 0.f);
            const int p = g * 4 + r, f = t * 16 + p16;
            T[p * 64 + swz(f, p)] = (_Float16)v;
        }
    }
}

__global__ __launch_bounds__(256) void ngp_mlp_mfma(
    const _Float16* __restrict__ embws,      // [N][32] f16
    const float4* __restrict__ dS,
    const _Float16* __restrict__ frags,
    const float* __restrict__ fb1, const float* __restrict__ fb2, const float* __restrict__ fb3,
    const float* __restrict__ rb1, const float* __restrict__ rb2, const float* __restrict__ rb3,
    const float* __restrict__ rb4,
    float* __restrict__ out, int N)
{
    __shared__ _Float16 tbuf[4][16 * 64];
    __shared__ float obuf[4][64];
    const int tid = threadIdx.x;
    const int wv = tid >> 6, l = tid & 63;
    const int p16 = l & 15, g = l >> 4;
    const int base = (blockIdx.x * 4 + wv) * 16;
    _Float16* T = tbuf[wv];
    float* O = obuf[wv];

    int pidx = base + p16; if (pidx >= N) pidx = N - 1;
    const float4 d4 = dS[pidx];

    // ---- L1: A straight from packed emb ----
    half8 a0 = *reinterpret_cast<const half8*>(embws + (size_t)pidx * 32 + g * 8);
    f32x4 acc[4];
    half8 a1[2];

    #pragma unroll
    for (int t = 0; t < 4; ++t) {
        const float b = fb1[t * 16 + p16];
        f32x4 c = {b, b, b, b};
        acc[t] = __builtin_amdgcn_mfma_f32_16x16x32_f16(a0, ldfrag(frags, FO_L1 + t * 512, l), c, 0, 0, 0);
    }
    storeD4<true>(T, acc, p16, g);
    a1[0] = loadA(T, p16, g * 8); a1[1] = loadA(T, p16, 32 + g * 8);

    // ---- L2 ----
    #pragma unroll
    for (int t = 0; t < 4; ++t) {
        const float b = fb2[t * 16 + p16];
        f32x4 c = {b, b, b, b};
        c = __builtin_amdgcn_mfma_f32_16x16x32_f16(a1[0], ldfrag(frags, FO_L2 + (t * 2 + 0) * 512, l), c, 0, 0, 0);
        acc[t] = __builtin_amdgcn_mfma_f32_16x16x32_f16(a1[1], ldfrag(frags, FO_L2 + (t * 2 + 1) * 512, l), c, 0, 0, 0);
    }
    storeD4<true>(T, acc, p16, g);
    a1[0] = loadA(T, p16, g * 8); a1[1] = loadA(T, p16, 32 + g * 8);

    // ---- L3 (feat, 16-wide) ----
    {
        const float b = fb3[p16];
        f32x4 c = {b, b, b, b};
        c = __builtin_amdgcn_mfma_f32_16x16x32_f16(a1[0], ldfrag(frags, FO_L3 + 0, l), c, 0, 0, 0);
        c = __builtin_amdgcn_mfma_f32_16x16x32_f16(a1[1], ldfrag(frags, FO_L3 + 512, l), c, 0, 0, 0);
        if (p16 == 0) {
            #pragma unroll
            for (int r = 0; r < 4; ++r) O[(g * 4 + r) * 4 + 3] = __expf(c[r]);
        }
        #pragma unroll
        for (int r = 0; r < 4; ++r) {
            const int p = g * 4 + r, f = p16;
            T[p * 64 + swz(f, p)] = (_Float16)c[r];
        }
    }

    // ---- PE fill: features 16..31 ----
    {
        const float dx = d4.x, dy = d4.y, dz = d4.z;
        float pv0, pv1, pv2, pv3;
        if (g == 0)      { pv0 = dx;              pv1 = dy;          pv2 = dz;              pv3 = __sinf(dx); }
        else if (g == 1) { pv0 = __sinf(2.f*dx);  pv1 = __sinf(dy);  pv2 = __sinf(2.f*dy);  pv3 = __sinf(dz); }
        else if (g == 2) { pv0 = __sinf(2.f*dz);  pv1 = __cosf(dx);  pv2 = __cosf(2.f*dx);  pv3 = __cosf(dy); }
        else             { pv0 = __cosf(2.f*dy);  pv1 = __cosf(dz);  pv2 = __cosf(2.f*dz);  pv3 = 0.f; }
        const float pv[4] = {pv0, pv1, pv2, pv3};
        #pragma unroll
        for (int j = 0; j < 4; ++j) {
            const int f = 16 + g * 4 + j;
            T[p16 * 64 + swz(f, p16)] = (_Float16)pv[j];
        }
    }
    half8 ar = loadA(T, p16, g * 8);

    // ---- R1 (K=32) ----
    #pragma unroll
    for (int t = 0; t < 4; ++t) {
        const float b = rb1[t * 16 + p16];
        f32x4 c = {b, b, b, b};
        acc[t] = __builtin_amdgcn_mfma_f32_16x16x32_f16(ar, ldfrag(frags, FO_R1 + t * 512, l), c, 0, 0, 0);
    }
    storeD4<true>(T, acc, p16, g);
    a1[0] = loadA(T, p16, g * 8); a1[1] = loadA(T, p16, 32 + g * 8);

    // ---- R2 ----
    #pragma unroll
    for (int t = 0; t < 4; ++t) {
        const float b = rb2[t * 16 + p16];
        f32x4 c = {b, b, b, b};
        c = __builtin_amdgcn_mfma_f32_16x16x32_f16(a1[0], ldfrag(frags, FO_R2 + (t * 2 + 0) * 512, l), c, 0, 0, 0);
        acc[t] = __builtin_amdgcn_mfma_f32_16x16x32_f16(a1[1], ldfrag(frags, FO_R2 + (t * 2 + 1) * 512, l), c, 0, 0, 0);
    }
    storeD4<true>(T, acc, p16, g);
    a1[0] = loadA(T, p16, g * 8); a1[1] = loadA(T, p16, 32 + g * 8);

    // ---- R3 ----
    #pragma unroll
    for (int t = 0; t < 4; ++t) {
        const float b = rb3[t * 16 + p16];
        f32x4 c = {b, b, b, b};
        c = __builtin_amdgcn_mfma_f32_16x16x32_f16(a1[0], ldfrag(frags, FO_R3 + (t * 2 + 0) * 512, l), c, 0, 0, 0);
        acc[t] = __builtin_amdgcn_mfma_f32_16x16x32_f16(a1[1], ldfrag(frags, FO_R3 + (t * 2 + 1) * 512, l), c, 0, 0, 0);
    }
    storeD4<true>(T, acc, p16, g);
    a1[0] = loadA(T, p16, g * 8); a1[1] = loadA(T, p16, 32 + g * 8);

    // ---- R4 (rgb, 3 cols of one 16-wide tile) ----
    {
        const float b = (p16 < 3) ? rb4[p16] : 0.f;
        f32x4 c = {b, b, b, b};
        c = __builtin_amdgcn_mfma_f32_16x16x32_f16(a1[0], ldfrag(frags, FO_R4 + 0, l), c, 0, 0, 0);
        c = __builtin_amdgcn_mfma_f32_16x16x32_f16(a1[1], ldfrag(frags, FO_R4 + 512, l), c, 0, 0, 0);
        if (p16 < 3) {
            #pragma unroll
            for (int r = 0; r < 4; ++r)
                O[(g * 4 + r) * 4 + p16] = 1.f / (1.f + __expf(-c[r]));
        }
    }

    // ---- scatter out ----
    if (base + p16 < N) {
        const unsigned orig = __float_as_uint(d4.w);
        out[(size_t)orig * 4 + g] = O[p16 * 4 + g];
    }
}

// ---------------- fused fallback (small ws) ----------------
template<int NIN, int NOUT, bool RELU>
__device__ __forceinline__ void dense_l(const float* __restrict__ W, const float* __restrict__ Bias,
                                        const float* __restrict__ col, float (&out)[NOUT])
{
    #pragma unroll
    for (int j = 0; j < NOUT; ++j) out[j] = Bias[j];
    #pragma unroll 4
    for (int i = 0; i < NIN; ++i) {
        const float a = col[i * BLK];
        const float* Wr = W + i * NOUT;
        #pragma unroll
        for (int j = 0; j < NOUT; ++j) out[j] = fmaf(a, Wr[j], out[j]);
    }
    if (RELU) {
        #pragma unroll
        for (int j = 0; j < NOUT; ++j) out[j] = fmaxf(out[j], 0.f);
    }
}

__device__ __forceinline__ float4 mlp_lds(float* col, float dx0, float dy0, float dz0,
    const float* __restrict__ fw1, const float* __restrict__ fb1,
    const float* __restrict__ fw2, const float* __restrict__ fb2,
    const float* __restrict__ fw3, const float* __restrict__ fb3,
    const float* __restrict__ rw1, const float* __restrict__ rb1,
    const float* __restrict__ rw2, const float* __restrict__ rb2,
    const float* __restrict__ rw3, const float* __restrict__ rb3,
    const float* __restrict__ rw4, const float* __restrict__ rb4)
{
    float h[64];
    dense_l<32, 64, true>(fw1, fb1, col, h);
    #pragma unroll
    for (int j = 0; j < 64; ++j) col[j * BLK] = h[j];
    dense_l<64, 64, true>(fw2, fb2, col, h);
    #pragma unroll
    for (int j = 0; j < 64; ++j) col[j * BLK] = h[j];
    float feat16[16];
    dense_l<64, 16, false>(fw3, fb3, col, feat16);
    const float sigma = expf(feat16[0]);
    #pragma unroll
    for (int j = 0; j < 16; ++j) col[j * BLK] = feat16[j];
    col[16 * BLK] = dx0; col[17 * BLK] = dy0; col[18 * BLK] = dz0;
    {
        float s, c;
        sincosf(dx0,     &s, &c); col[19 * BLK] = s; col[25 * BLK] = c;
        sincosf(2.f*dx0, &s, &c); col[20 * BLK] = s; col[26 * BLK] = c;
        sincosf(dy0,     &s, &c); col[21 * BLK] = s; col[27 * BLK] = c;
        sincosf(2.f*dy0, &s, &c); col[22 * BLK] = s; col[28 * BLK] = c;
        sincosf(dz0,     &s, &c); col[23 * BLK] = s; col[29 * BLK] = c;
        sincosf(2.f*dz0, &s, &c); col[24 * BLK] = s; col[30 * BLK] = c;
    }
    dense_l<31, 64, true>(rw1, rb1, col, h);
    #pragma unroll
    for (int j = 0; j < 64; ++j) col[j * BLK] = h[j];
    dense_l<64, 64, true>(rw2, rb2, col, h);
    #pragma unroll
    for (int j = 0; j < 64; ++j) col[j * BLK] = h[j];
    dense_l<64, 64, true>(rw3, rb3, col, h);
    #pragma unroll
    for (int j = 0; j < 64; ++j) col[j * BLK] = h[j];
    float o0 = rb4[0], o1 = rb4[1], o2 = rb4[2];
    #pragma unroll 4
    for (int i = 0; i < 64; ++i) {
        const float a = col[i * BLK];
        o0 = fmaf(a, rw4[i*3 + 0], o0);
        o1 = fmaf(a, rw4[i*3 + 1], o1);
        o2 = fmaf(a, rw4[i*3 + 2], o2);
    }
    o0 = 1.f / (1.f + expf(-o0));
    o1 = 1.f / (1.f + expf(-o1));
    o2 = 1.f / (1.f + expf(-o2));
    return make_float4(o0, o1, o2, sigma);
}

template<bool HALF_TABLE>
__global__ __launch_bounds__(BLK) void ngp_fused(
    const float* __restrict__ coords,
    const float* __restrict__ dirs,
    const float* __restrict__ tableF,
    const __half2* __restrict__ tableH,
    const float* __restrict__ fw1, const float* __restrict__ fb1,
    const float* __restrict__ fw2, const float* __restrict__ fb2,
    const float* __restrict__ fw3, const float* __restrict__ fb3,
    const float* __restrict__ rw1, const float* __restrict__ rb1,
    const float* __restrict__ rw2, const float* __restrict__ rb2,
    const float* __restrict__ rw3, const float* __restrict__ rb3,
    const float* __restrict__ rw4, const float* __restrict__ rb4,
    float* __restrict__ out, int N)
{
    __shared__ float sbuf[64 * BLK];
    const int tid = threadIdx.x;
    const int gi  = blockIdx.x * BLK + tid;
    if (gi >= N) return;

    float emb[32];
    encode_point<HALF_TABLE>(coords[3*gi+0], coords[3*gi+1], coords[3*gi+2],
                             tableF, tableH, emb);
    float* col = sbuf + tid;
    #pragma unroll
    for (int j = 0; j < 32; ++j) col[j * BLK] = emb[j];

    const float4 ov = mlp_lds(col, dirs[3*gi+0], dirs[3*gi+1], dirs[3*gi+2],
                              fw1, fb1, fw2, fb2, fw3, fb3,
                              rw1, rb1, rw2, rb2, rw3, rb3, rw4, rb4);
    reinterpret_cast<float4*>(out)[gi] = ov;
}

extern "C" void kernel_launch(void* const* d_in, const int* in_sizes, int n_in,
                              void* d_out, int out_size, void* d_ws, size_t ws_size,
                              hipStream_t stream)
{
    const float* coords = (const float*)d_in[0];
    const float* dirs   = (const float*)d_in[1];
    const float* table  = (const float*)d_in[2];
    const float* fw1 = (const float*)d_in[3];
    const float* fb1 = (const float*)d_in[4];
    const float* fw2 = (const float*)d_in[5];
    const float* fb2 = (const float*)d_in[6];
    const float* fw3 = (const float*)d_in[7];
    const float* fb3 = (const float*)d_in[8];
    const float* rw1 = (const float*)d_in[9];
    const float* rb1 = (const float*)d_in[10];
    const float* rw2 = (const float*)d_in[11];
    const float* rb2 = (const float*)d_in[12];
    const float* rw3 = (const float*)d_in[13];
    const float* rb3 = (const float*)d_in[14];
    const float* rw4 = (const float*)d_in[15];
    const float* rb4 = (const float*)d_in[16];

    const int N = in_sizes[0] / 3;
    const int table_floats = in_sizes[2];

    // ws layout
    size_t pos = 0;
    auto take = [&](size_t bytes) { size_t p = pos; pos = (pos + bytes + 255) & ~(size_t)255; return p; };
    const size_t o_tableH = take((size_t)table_floats * 2);
    const size_t o_emb    = take((size_t)N * 64);
    const size_t o_cS     = take((size_t)N * 16);
    const size_t o_dS     = take((size_t)N * 16);
    const size_t o_hist   = take((size_t)NBINS * 4);
    const size_t o_cursor = take((size_t)NBINS * 4);
    const size_t o_bsum   = take(256 * 4);
    const size_t o_frag   = take((size_t)FRAG_TOTAL * 2);
    const size_t need_full = pos;
    const size_t need_half = (size_t)table_floats * 2;

    char* ws = (char*)d_ws;

    if (ws_size >= need_full) {
        __half*    tableH = (__half*)(ws + o_tableH);
        uint4*     embws  = (uint4*)(ws + o_emb);
        float4*    cS     = (float4*)(ws + o_cS);
        float4*    dS     = (float4*)(ws + o_dS);
        unsigned*  hist   = (unsigned*)(ws + o_hist);
        unsigned*  cursor = (unsigned*)(ws + o_cursor);
        unsigned*  bsum   = (unsigned*)(ws + o_bsum);
        _Float16*  frag   = (_Float16*)(ws + o_frag);

        hipLaunchKernelGGL(cvt_table, dim3(2048), dim3(256), 0, stream,
                           table, tableH, table_floats);
        hipLaunchKernelGGL(prep_frags, dim3(FRAG_TOTAL / 256), dim3(256), 0, stream,
                           fw1, fw2, fw3, rw1, rw2, rw3, rw4, frag);
        hipMemsetAsync(hist, 0, (size_t)NBINS * 4, stream);
        hipLaunchKernelGGL(hist_build, dim3((N + 255) / 256), dim3(256), 0, stream,
                           coords, hist, N);
        hipLaunchKernelGGL(scan1, dim3(NBINS / 1024), dim3(256), 0, stream, hist, bsum);
        hipLaunchKernelGGL(scan2, dim3(1), dim3(256), 0, stream, bsum);
        hipLaunchKernelGGL(scan3, dim3(NBINS / 256), dim3(256), 0, stream, hist, bsum, cursor);
        hipLaunchKernelGGL(scatter_pts, dim3((N + 255) / 256), dim3(256), 0, stream,
                           coords, dirs, cursor, cS, dS, N);
        hipLaunchKernelGGL((ngp_encode<true>), dim3((N + EBLK - 1) / EBLK), dim3(EBLK), 0, stream,
                           cS, table, (const __half2*)tableH, embws, N);
        hipLaunchKernelGGL(ngp_mlp_mfma, dim3((N + 63) / 64), dim3(256), 0, stream,
                           (const _Float16*)embws, dS, frag,
                           fb1, fb2, fb3, rb1, rb2, rb3, rb4,
                           (float*)d_out, N);
    } else if (ws_size >= need_half) {
        __half* tableH = (__half*)ws;
        hipLaunchKernelGGL(cvt_table, dim3(2048), dim3(256), 0, stream,
                           table, tableH, table_floats);
        hipLaunchKernelGGL((ngp_fused<true>), dim3((N + BLK - 1) / BLK), dim3(BLK), 0, stream,
                           coords, dirs, table, (const __half2*)tableH,
                           fw1, fb1, fw2, fb2, fw3, fb3,
                           rw1, rb1, rw2, rb2, rw3, rb3, rw4, rb4,
                           (float*)d_out, N);
    } else {
        hipLaunchKernelGGL((ngp_fused<false>), dim3((N + BLK - 1) / BLK), dim3(BLK), 0, stream,
                           coords, dirs, table, (const __half2*)nullptr,
                           fw1, fb1, fw2, fb2, fw3, fb3,
                           rw1, rb1, rw2, rb2, rw3, rb3, rw4, rb4,
                           (float*)d_out, N);
    }
}

// Round 6
// 924.486 us; speedup vs baseline: 2.8082x; 1.1051x over previous
//
#include <hip/hip_runtime.h>
#include <hip/hip_fp16.h>
#include <math.h>

#define BLK 128          // fused-fallback block
#define EBLK 256         // encode / utility block
#define NBINS (1 << 18)  // 6 bits per axis, Morton
#define Q_SCALE 65536.0f
#define Q_DESCALE 0x1p-16f

typedef __attribute__((ext_vector_type(8))) _Float16 half8;
typedef __attribute__((ext_vector_type(4))) float f32x4;
typedef __attribute__((ext_vector_type(2))) float f32x2;

// frag offsets in f16 elements: L1,L2,L3,R1,R2,R3,R4
#define FO_L1 0
#define FO_L2 2048
#define FO_L3 6144
#define FO_R1 7168
#define FO_R2 9216
#define FO_R3 13312
#define FO_R4 17408
#define FRAG_TOTAL 18432

// ---------------- Morton key ----------------
__device__ __forceinline__ unsigned mexp(unsigned v) {
    v &= 0x3FF;
    v = (v | (v << 16)) & 0x030000FF;
    v = (v | (v << 8))  & 0x0300F00F;
    v = (v | (v << 4))  & 0x030C30C3;
    v = (v | (v << 2))  & 0x09249249;
    return v;
}
__device__ __forceinline__ unsigned morton_key(float x, float y, float z) {
    int bx = (int)(x * 64.f); bx = bx < 0 ? 0 : (bx > 63 ? 63 : bx);
    int by = (int)(y * 64.f); by = by < 0 ? 0 : (by > 63 ? 63 : by);
    int bz = (int)(z * 64.f); bz = bz < 0 ? 0 : (bz > 63 ? 63 : bz);
    return (mexp((unsigned)bx) << 2) | (mexp((unsigned)by) << 1) | mexp((unsigned)bz);
}

// ---------------- table f32 -> fp8(e4m3, x2^16) ----------------
// each thread converts one float4 = 2 entries -> 4 fp8 bytes = 1 uint
__global__ __launch_bounds__(256) void cvt_table_fp8(const float4* __restrict__ src,
                                                     unsigned* __restrict__ dst, int npair)
{
    int i = blockIdx.x * 256 + threadIdx.x;
    const int stride = gridDim.x * 256;
    for (; i < npair; i += stride) {
        const float4 v = src[i];
        const int lo = __builtin_amdgcn_cvt_pk_fp8_f32(v.x * Q_SCALE, v.y * Q_SCALE, 0, false);
        const int hi = __builtin_amdgcn_cvt_pk_fp8_f32(v.z * Q_SCALE, v.w * Q_SCALE, 0, false);
        dst[i] = ((unsigned)lo & 0xFFFFu) | (((unsigned)hi & 0xFFFFu) << 16);
    }
}

// ---------------- weight fragment packing ----------------
__global__ __launch_bounds__(256) void prep_frags(
    const float* __restrict__ fw1, const float* __restrict__ fw2, const float* __restrict__ fw3,
    const float* __restrict__ rw1, const float* __restrict__ rw2, const float* __restrict__ rw3,
    const float* __restrict__ rw4, _Float16* __restrict__ frag)
{
    const int gid = blockIdx.x * 256 + threadIdx.x;
    if (gid >= FRAG_TOTAL) return;
    constexpr int offs[8] = {FO_L1, FO_L2, FO_L3, FO_R1, FO_R2, FO_R3, FO_R4, FRAG_TOTAL};
    constexpr int Ks[7]   = {32, 64, 64, 31, 64, 64, 64};
    constexpr int NO[7]   = {64, 64, 16, 64, 64, 64, 3};
    constexpr int NKs[7]  = {1, 2, 2, 1, 2, 2, 2};
    int layer = 0;
    #pragma unroll
    for (int i = 1; i < 7; ++i) if (gid >= offs[i]) layer = i;
    const float* W = fw1;
    if (layer == 1) W = fw2; else if (layer == 2) W = fw3;
    else if (layer == 3) W = rw1; else if (layer == 4) W = rw2;
    else if (layer == 5) W = rw3; else if (layer == 6) W = rw4;

    const int e = gid - offs[layer];
    const int nk = NKs[layer];
    const int blk = e >> 9, within = e & 511;
    const int t = blk / nk, ks = blk - t * nk;
    const int lane = within >> 3, i = within & 7;
    const int k = ks * 32 + (lane >> 4) * 8 + i;
    const int col = t * 16 + (lane & 15);
    float v = 0.f;
    if (k < Ks[layer] && col < NO[layer]) v = W[k * NO[layer] + col];
    frag[gid] = (_Float16)v;
}

// ---------------- sort: histogram ----------------
__global__ __launch_bounds__(256) void hist_build(const float* __restrict__ coords,
                                                  unsigned* __restrict__ hist, int N)
{
    const int i = blockIdx.x * 256 + threadIdx.x;
    if (i >= N) return;
    const unsigned key = morton_key(coords[3*i+0], coords[3*i+1], coords[3*i+2]);
    atomicAdd(&hist[key], 1u);
}

// ---------------- sort: hierarchical exclusive scan ----------------
__global__ __launch_bounds__(256) void scan1(unsigned* __restrict__ hist, unsigned* __restrict__ bsum)
{
    __shared__ unsigned sa[256], sb[256];
    const int t = threadIdx.x;
    const unsigned base = blockIdx.x * 1024u + (unsigned)t * 4u;
    const unsigned v0 = hist[base+0], v1 = hist[base+1], v2 = hist[base+2], v3 = hist[base+3];
    const unsigned sum = v0 + v1 + v2 + v3;
    sa[t] = sum; __syncthreads();
    unsigned* src = sa; unsigned* dst = sb;
    for (int off = 1; off < 256; off <<= 1) {
        dst[t] = src[t] + (t >= off ? src[t - off] : 0u);
        __syncthreads();
        unsigned* tmp = src; src = dst; dst = tmp;
    }
    const unsigned incl = src[t];
    unsigned run = incl - sum;
    hist[base+0] = run; run += v0;
    hist[base+1] = run; run += v1;
    hist[base+2] = run; run += v2;
    hist[base+3] = run;
    if (t == 255) bsum[blockIdx.x] = incl;
}

__global__ __launch_bounds__(256) void scan2(unsigned* __restrict__ bsum)
{
    __shared__ unsigned sa[256], sb[256];
    const int t = threadIdx.x;
    const unsigned v = bsum[t];
    sa[t] = v; __syncthreads();
    unsigned* src = sa; unsigned* dst = sb;
    for (int off = 1; off < 256; off <<= 1) {
        dst[t] = src[t] + (t >= off ? src[t - off] : 0u);
        __syncthreads();
        unsigned* tmp = src; src = dst; dst = tmp;
    }
    bsum[t] = src[t] - v;
}

__global__ __launch_bounds__(256) void scan3(const unsigned* __restrict__ hist,
                                             const unsigned* __restrict__ bsum,
                                             unsigned* __restrict__ cursor)
{
    const int i = blockIdx.x * 256 + threadIdx.x;
    cursor[i] = hist[i] + bsum[i >> 10];
}

// ---------------- sort: scatter points into bins ----------------
__global__ __launch_bounds__(256) void scatter_pts(const float* __restrict__ coords,
                                                   const float* __restrict__ dirs,
                                                   unsigned* __restrict__ cursor,
                                                   float4* __restrict__ cS,
                                                   float4* __restrict__ dS, int N)
{
    const int i = blockIdx.x * 256 + threadIdx.x;
    if (i >= N) return;
    const float x = coords[3*i+0], y = coords[3*i+1], z = coords[3*i+2];
    const unsigned key = morton_key(x, y, z);
    const unsigned slot = atomicAdd(&cursor[key], 1u);
    cS[slot] = make_float4(x, y, z, __uint_as_float((unsigned)i));
    dS[slot] = make_float4(dirs[3*i+0], dirs[3*i+1], dirs[3*i+2], __uint_as_float((unsigned)i));
}

// ---------------- per-level geometry ----------------
#define LVL_CONSTS \
    constexpr int RES[16] = {32,38,46,55,67,80,97,116,140,168,203,244,294,353,425,512}; \
    constexpr int DN [16] = {1,1,1,1,1,1,1,1,1,1,1,1,0,0,0,0}; \
    constexpr int OFF[16] = {0,35937,95256,199079,374695,689127,1220568,2161760, \
                             3763373,6566594,11393403,19883067,34589192,35113480, \
                             35637768,36162056}; \
    constexpr unsigned NMASK = (1u << 19) - 1u;

__device__ __forceinline__ void corner_idx(int l, int res, bool dense,
                                           int cx, int cy, int cz, int (&idx)[8])
{
    constexpr unsigned NMASK2 = (1u << 19) - 1u;
    #pragma unroll
    for (int c = 0; c < 8; ++c) {
        const int dx = (c >> 2) & 1, dy = (c >> 1) & 1, dz = c & 1;
        if (dense) {
            idx[c] = (cx + dx) + (cy + dy) * (res + 1) + (cz + dz) * (res + 1) * (res + 1);
        } else {
            const unsigned ux = (unsigned)(cx + dx);
            const unsigned uy = (unsigned)(cy + dy);
            const unsigned uz = (unsigned)(cz + dz);
            const unsigned hh = ux ^ (uy * 2654435761u) ^ (uz * 805459861u);
            idx[c] = (int)(hh & NMASK2);
        }
    }
}

// ---------------- fp8 encode for one point ----------------
__device__ __forceinline__ void encode_point_q(float x, float y, float z,
                                               const unsigned short* __restrict__ tableQ,
                                               float (&emb)[32])
{
    LVL_CONSTS
    #pragma unroll
    for (int l = 0; l < 16; ++l) {
        const int res = RES[l];
        const float xl = x * (float)res, yl = y * (float)res, zl = z * (float)res;
        int cx = (int)floorf(xl); cx = cx < 0 ? 0 : (cx > res-1 ? res-1 : cx);
        int cy = (int)floorf(yl); cy = cy < 0 ? 0 : (cy > res-1 ? res-1 : cy);
        int cz = (int)floorf(zl); cz = cz < 0 ? 0 : (cz > res-1 ? res-1 : cz);
        const float wx = xl - (float)cx, wy = yl - (float)cy, wz = zl - (float)cz;

        int idx[8];
        corner_idx(l, res, DN[l] != 0, cx, cy, cz, idx);

        unsigned qv[8];
        #pragma unroll
        for (int c = 0; c < 8; ++c) qv[c] = tableQ[OFF[l] + idx[c]];

        float e0 = 0.f, e1 = 0.f;
        #pragma unroll
        for (int c = 0; c < 8; ++c) {
            const int dx = (c >> 2) & 1, dy = (c >> 1) & 1, dz = c & 1;
            const float w = (dx ? wx : 1.f - wx) * (dy ? wy : 1.f - wy) * (dz ? wz : 1.f - wz);
            const f32x2 vf = __builtin_amdgcn_cvt_pk_f32_fp8((int)qv[c], false);
            e0 = fmaf(vf.x, w, e0);
            e1 = fmaf(vf.y, w, e1);
        }
        emb[2*l+0] = e0 * Q_DESCALE;
        emb[2*l+1] = e1 * Q_DESCALE;
    }
}

// ---------------- f32 encode (fallback) ----------------
__device__ __forceinline__ void encode_point_f(float x, float y, float z,
                                               const float* __restrict__ tableF,
                                               float (&emb)[32])
{
    LVL_CONSTS
    #pragma unroll
    for (int l = 0; l < 16; ++l) {
        const int res = RES[l];
        const float xl = x * (float)res, yl = y * (float)res, zl = z * (float)res;
        int cx = (int)floorf(xl); cx = cx < 0 ? 0 : (cx > res-1 ? res-1 : cx);
        int cy = (int)floorf(yl); cy = cy < 0 ? 0 : (cy > res-1 ? res-1 : cy);
        int cz = (int)floorf(zl); cz = cz < 0 ? 0 : (cz > res-1 ? res-1 : cz);
        const float wx = xl - (float)cx, wy = yl - (float)cy, wz = zl - (float)cz;
        int idx[8];
        corner_idx(l, res, DN[l] != 0, cx, cy, cz, idx);
        float e0 = 0.f, e1 = 0.f;
        #pragma unroll
        for (int c = 0; c < 8; ++c) {
            const int dx = (c >> 2) & 1, dy = (c >> 1) & 1, dz = c & 1;
            const float w = (dx ? wx : 1.f - wx) * (dy ? wy : 1.f - wy) * (dz ? wz : 1.f - wz);
            const float2 v = *reinterpret_cast<const float2*>(tableF + (size_t)2 * (size_t)(OFF[l] + idx[c]));
            e0 = fmaf(v.x, w, e0);
            e1 = fmaf(v.y, w, e1);
        }
        emb[2*l+0] = e0;
        emb[2*l+1] = e1;
    }
}

// ---------------- encode kernel (sorted input, fp8 table, XCD-chunked) ----------------
__global__ __launch_bounds__(EBLK, 8) void ngp_encode(
    const float4* __restrict__ cS,
    const unsigned short* __restrict__ tableQ,
    uint4* __restrict__ emb_out, int N)
{
    // bijective XCD-contiguous remap of blockIdx (8 XCDs)
    const unsigned nwg = gridDim.x;
    const unsigned bid = blockIdx.x;
    const unsigned qn = nwg >> 3, rn = nwg & 7;
    const unsigned xc = bid & 7, ib = bid >> 3;
    const unsigned nb = (xc < rn ? xc * (qn + 1) : rn * (qn + 1) + (xc - rn) * qn) + ib;

    const int gi = (int)(nb * EBLK + threadIdx.x);
    if (gi >= N) return;

    const float4 c = cS[gi];
    float emb[32];
    encode_point_q(c.x, c.y, c.z, tableQ, emb);

    unsigned packed[16];
    #pragma unroll
    for (int i = 0; i < 16; ++i) {
        const __half2 h = __floats2half2_rn(emb[2*i+0], emb[2*i+1]);
        packed[i] = *reinterpret_cast<const unsigned*>(&h);
    }
    uint4* dst = emb_out + (size_t)gi * 4;
    #pragma unroll
    for (int k = 0; k < 4; ++k)
        dst[k] = make_uint4(packed[4*k+0], packed[4*k+1], packed[4*k+2], packed[4*k+3]);
}

// ================= MFMA MLP =================
__device__ __forceinline__ half8 ldfrag(const _Float16* __restrict__ frags, int off, int l) {
    return *reinterpret_cast<const half8*>(frags + off + l * 8);
}
__device__ __forceinline__ int swz(int f, int p) {
    return ((((f >> 3) + p) & 7) << 3) | (f & 7);
}
__device__ __forceinline__ half8 loadA(const _Float16* T, int p, int kb) {
    return *reinterpret_cast<const half8*>(T + p * 64 + ((((kb >> 3) + p) & 7) << 3));
}

template<bool RELU>
__device__ __forceinline__ void storeD4(_Float16* T, const f32x4 (&acc)[4], int p16, int g) {
    #pragma unroll
    for (int t = 0; t < 4; ++t) {
        #pragma unroll
        for (int r = 0; r < 4; ++r) {
            float v = acc[t][r];
            if (RELU) v = fmaxf(v, 0.f);
            const int p = g * 4 + r, f = t * 16 + p16;
            T[p * 64 + swz(f, p)] = (_Float16)v;
        }
    }
}

__global__ __launch_bounds__(256) void ngp_mlp_mfma(
    const _Float16* __restrict__ embws,      // [N][32] f16
    const float4* __restrict__ dS,
    const _Float16* __restrict__ frags,
    const float* __restrict__ fb1, const float* __restrict__ fb2, const float* __restrict__ fb3,
    const float* __restrict__ rb1, const float* __restrict__ rb2, const float* __restrict__ rb3,
    const float* __restrict__ rb4,
    float* __restrict__ out, int N)
{
    __shared__ _Float16 tbuf[4][16 * 64];
    __shared__ float obuf[4][64];
    const int tid = threadIdx.x;
    const int wv = tid >> 6, l = tid & 63;
    const int p16 = l & 15, g = l >> 4;
    const int base = (blockIdx.x * 4 + wv) * 16;
    _Float16* T = tbuf[wv];
    float* O = obuf[wv];

    int pidx = base + p16; if (pidx >= N) pidx = N - 1;
    const float4 d4 = dS[pidx];

    // ---- L1: A straight from packed emb ----
    half8 a0 = *reinterpret_cast<const half8*>(embws + (size_t)pidx * 32 + g * 8);
    f32x4 acc[4];
    half8 a1[2];

    __builtin_amdgcn_s_setprio(1);
    #pragma unroll
    for (int t = 0; t < 4; ++t) {
        const float b = fb1[t * 16 + p16];
        f32x4 c = {b, b, b, b};
        acc[t] = __builtin_amdgcn_mfma_f32_16x16x32_f16(a0, ldfrag(frags, FO_L1 + t * 512, l), c, 0, 0, 0);
    }
    __builtin_amdgcn_s_setprio(0);
    storeD4<true>(T, acc, p16, g);
    a1[0] = loadA(T, p16, g * 8); a1[1] = loadA(T, p16, 32 + g * 8);

    // ---- L2 ----
    __builtin_amdgcn_s_setprio(1);
    #pragma unroll
    for (int t = 0; t < 4; ++t) {
        const float b = fb2[t * 16 + p16];
        f32x4 c = {b, b, b, b};
        c = __builtin_amdgcn_mfma_f32_16x16x32_f16(a1[0], ldfrag(frags, FO_L2 + (t * 2 + 0) * 512, l), c, 0, 0, 0);
        acc[t] = __builtin_amdgcn_mfma_f32_16x16x32_f16(a1[1], ldfrag(frags, FO_L2 + (t * 2 + 1) * 512, l), c, 0, 0, 0);
    }
    __builtin_amdgcn_s_setprio(0);
    storeD4<true>(T, acc, p16, g);
    a1[0] = loadA(T, p16, g * 8); a1[1] = loadA(T, p16, 32 + g * 8);

    // ---- L3 (feat, 16-wide) ----
    {
        const float b = fb3[p16];
        f32x4 c = {b, b, b, b};
        __builtin_amdgcn_s_setprio(1);
        c = __builtin_amdgcn_mfma_f32_16x16x32_f16(a1[0], ldfrag(frags, FO_L3 + 0, l), c, 0, 0, 0);
        c = __builtin_amdgcn_mfma_f32_16x16x32_f16(a1[1], ldfrag(frags, FO_L3 + 512, l), c, 0, 0, 0);
        __builtin_amdgcn_s_setprio(0);
        if (p16 == 0) {
            #pragma unroll
            for (int r = 0; r < 4; ++r) O[(g * 4 + r) * 4 + 3] = __expf(c[r]);
        }
        #pragma unroll
        for (int r = 0; r < 4; ++r) {
            const int p = g * 4 + r, f = p16;
            T[p * 64 + swz(f, p)] = (_Float16)c[r];
        }
    }

    // ---- PE fill: features 16..31 ----
    {
        const float dx = d4.x, dy = d4.y, dz = d4.z;
        float pv0, pv1, pv2, pv3;
        if (g == 0)      { pv0 = dx;              pv1 = dy;          pv2 = dz;              pv3 = __sinf(dx); }
        else if (g == 1) { pv0 = __sinf(2.f*dx);  pv1 = __sinf(dy);  pv2 = __sinf(2.f*dy);  pv3 = __sinf(dz); }
        else if (g == 2) { pv0 = __sinf(2.f*dz);  pv1 = __cosf(dx);  pv2 = __cosf(2.f*dx);  pv3 = __cosf(dy); }
        else             { pv0 = __cosf(2.f*dy);  pv1 = __cosf(dz);  pv2 = __cosf(2.f*dz);  pv3 = 0.f; }
        const float pv[4] = {pv0, pv1, pv2, pv3};
        #pragma unroll
        for (int j = 0; j < 4; ++j) {
            const int f = 16 + g * 4 + j;
            T[p16 * 64 + swz(f, p16)] = (_Float16)pv[j];
        }
    }
    half8 ar = loadA(T, p16, g * 8);

    // ---- R1 (K=32) ----
    __builtin_amdgcn_s_setprio(1);
    #pragma unroll
    for (int t = 0; t < 4; ++t) {
        const float b = rb1[t * 16 + p16];
        f32x4 c = {b, b, b, b};
        acc[t] = __builtin_amdgcn_mfma_f32_16x16x32_f16(ar, ldfrag(frags, FO_R1 + t * 512, l), c, 0, 0, 0);
    }
    __builtin_amdgcn_s_setprio(0);
    storeD4<true>(T, acc, p16, g);
    a1[0] = loadA(T, p16, g * 8); a1[1] = loadA(T, p16, 32 + g * 8);

    // ---- R2 ----
    __builtin_amdgcn_s_setprio(1);
    #pragma unroll
    for (int t = 0; t < 4; ++t) {
        const float b = rb2[t * 16 + p16];
        f32x4 c = {b, b, b, b};
        c = __builtin_amdgcn_mfma_f32_16x16x32_f16(a1[0], ldfrag(frags, FO_R2 + (t * 2 + 0) * 512, l), c, 0, 0, 0);
        acc[t] = __builtin_amdgcn_mfma_f32_16x16x32_f16(a1[1], ldfrag(frags, FO_R2 + (t * 2 + 1) * 512, l), c, 0, 0, 0);
    }
    __builtin_amdgcn_s_setprio(0);
    storeD4<true>(T, acc, p16, g);
    a1[0] = loadA(T, p16, g * 8); a1[1] = loadA(T, p16, 32 + g * 8);

    // ---- R3 ----
    __builtin_amdgcn_s_setprio(1);
    #pragma unroll
    for (int t = 0; t < 4; ++t) {
        const float b = rb3[t * 16 + p16];
        f32x4 c = {b, b, b, b};
        c = __builtin_amdgcn_mfma_f32_16x16x32_f16(a1[0], ldfrag(frags, FO_R3 + (t * 2 + 0) * 512, l), c, 0, 0, 0);
        acc[t] = __builtin_amdgcn_mfma_f32_16x16x32_f16(a1[1], ldfrag(frags, FO_R3 + (t * 2 + 1) * 512, l), c, 0, 0, 0);
    }
    __builtin_amdgcn_s_setprio(0);
    storeD4<true>(T, acc, p16, g);
    a1[0] = loadA(T, p16, g * 8); a1[1] = loadA(T, p16, 32 + g * 8);

    // ---- R4 (rgb, 3 cols of one 16-wide tile) ----
    {
        const float b = (p16 < 3) ? rb4[p16] : 0.f;
        f32x4 c = {b, b, b, b};
        __builtin_amdgcn_s_setprio(1);
        c = __builtin_amdgcn_mfma_f32_16x16x32_f16(a1[0], ldfrag(frags, FO_R4 + 0, l), c, 0, 0, 0);
        c = __builtin_amdgcn_mfma_f32_16x16x32_f16(a1[1], ldfrag(frags, FO_R4 + 512, l), c, 0, 0, 0);
        __builtin_amdgcn_s_setprio(0);
        if (p16 < 3) {
            #pragma unroll
            for (int r = 0; r < 4; ++r)
                O[(g * 4 + r) * 4 + p16] = 1.f / (1.f + __expf(-c[r]));
        }
    }

    // ---- scatter out ----
    if (base + p16 < N) {
        const unsigned orig = __float_as_uint(d4.w);
        out[(size_t)orig * 4 + g] = O[p16 * 4 + g];
    }
}

// ---------------- fused fallback (small ws, f32 table) ----------------
template<int NIN, int NOUT, bool RELU>
__device__ __forceinline__ void dense_l(const float* __restrict__ W, const float* __restrict__ Bias,
                                        const float* __restrict__ col, float (&out)[NOUT])
{
    #pragma unroll
    for (int j = 0; j < NOUT; ++j) out[j] = Bias[j];
    #pragma unroll 4
    for (int i = 0; i < NIN; ++i) {
        const float a = col[i * BLK];
        const float* Wr = W + i * NOUT;
        #pragma unroll
        for (int j = 0; j < NOUT; ++j) out[j] = fmaf(a, Wr[j], out[j]);
    }
    if (RELU) {
        #pragma unroll
        for (int j = 0; j < NOUT; ++j) out[j] = fmaxf(out[j], 0.f);
    }
}

__device__ __forceinline__ float4 mlp_lds(float* col, float dx0, float dy0, float dz0,
    const float* __restrict__ fw1, const float* __restrict__ fb1,
    const float* __restrict__ fw2, const float* __restrict__ fb2,
    const float* __restrict__ fw3, const float* __restrict__ fb3,
    const float* __restrict__ rw1, const float* __restrict__ rb1,
    const float* __restrict__ rw2, const float* __restrict__ rb2,
    const float* __restrict__ rw3, const float* __restrict__ rb3,
    const float* __restrict__ rw4, const float* __restrict__ rb4)
{
    float h[64];
    dense_l<32, 64, true>(fw1, fb1, col, h);
    #pragma unroll
    for (int j = 0; j < 64; ++j) col[j * BLK] = h[j];
    dense_l<64, 64, true>(fw2, fb2, col, h);
    #pragma unroll
    for (int j = 0; j < 64; ++j) col[j * BLK] = h[j];
    float feat16[16];
    dense_l<64, 16, false>(fw3, fb3, col, feat16);
    const float sigma = expf(feat16[0]);
    #pragma unroll
    for (int j = 0; j < 16; ++j) col[j * BLK] = feat16[j];
    col[16 * BLK] = dx0; col[17 * BLK] = dy0; col[18 * BLK] = dz0;
    {
        float s, c;
        sincosf(dx0,     &s, &c); col[19 * BLK] = s; col[25 * BLK] = c;
        sincosf(2.f*dx0, &s, &c); col[20 * BLK] = s; col[26 * BLK] = c;
        sincosf(dy0,     &s, &c); col[21 * BLK] = s; col[27 * BLK] = c;
        sincosf(2.f*dy0, &s, &c); col[22 * BLK] = s; col[28 * BLK] = c;
        sincosf(dz0,     &s, &c); col[23 * BLK] = s; col[29 * BLK] = c;
        sincosf(2.f*dz0, &s, &c); col[24 * BLK] = s; col[30 * BLK] = c;
    }
    dense_l<31, 64, true>(rw1, rb1, col, h);
    #pragma unroll
    for (int j = 0; j < 64; ++j) col[j * BLK] = h[j];
    dense_l<64, 64, true>(rw2, rb2, col, h);
    #pragma unroll
    for (int j = 0; j < 64; ++j) col[j * BLK] = h[j];
    dense_l<64, 64, true>(rw3, rb3, col, h);
    #pragma unroll
    for (int j = 0; j < 64; ++j) col[j * BLK] = h[j];
    float o0 = rb4[0], o1 = rb4[1], o2 = rb4[2];
    #pragma unroll 4
    for (int i = 0; i < 64; ++i) {
        const float a = col[i * BLK];
        o0 = fmaf(a, rw4[i*3 + 0], o0);
        o1 = fmaf(a, rw4[i*3 + 1], o1);
        o2 = fmaf(a, rw4[i*3 + 2], o2);
    }
    o0 = 1.f / (1.f + expf(-o0));
    o1 = 1.f / (1.f + expf(-o1));
    o2 = 1.f / (1.f + expf(-o2));
    return make_float4(o0, o1, o2, sigma);
}

__global__ __launch_bounds__(BLK) void ngp_fused_f32(
    const float* __restrict__ coords,
    const float* __restrict__ dirs,
    const float* __restrict__ tableF,
    const float* __restrict__ fw1, const float* __restrict__ fb1,
    const float* __restrict__ fw2, const float* __restrict__ fb2,
    const float* __restrict__ fw3, const float* __restrict__ fb3,
    const float* __restrict__ rw1, const float* __restrict__ rb1,
    const float* __restrict__ rw2, const float* __restrict__ rb2,
    const float* __restrict__ rw3, const float* __restrict__ rb3,
    const float* __restrict__ rw4, const float* __restrict__ rb4,
    float* __restrict__ out, int N)
{
    __shared__ float sbuf[64 * BLK];
    const int tid = threadIdx.x;
    const int gi  = blockIdx.x * BLK + tid;
    if (gi >= N) return;

    float emb[32];
    encode_point_f(coords[3*gi+0], coords[3*gi+1], coords[3*gi+2], tableF, emb);
    float* col = sbuf + tid;
    #pragma unroll
    for (int j = 0; j < 32; ++j) col[j * BLK] = emb[j];

    const float4 ov = mlp_lds(col, dirs[3*gi+0], dirs[3*gi+1], dirs[3*gi+2],
                              fw1, fb1, fw2, fb2, fw3, fb3,
                              rw1, rb1, rw2, rb2, rw3, rb3, rw4, rb4);
    reinterpret_cast<float4*>(out)[gi] = ov;
}

extern "C" void kernel_launch(void* const* d_in, const int* in_sizes, int n_in,
                              void* d_out, int out_size, void* d_ws, size_t ws_size,
                              hipStream_t stream)
{
    const float* coords = (const float*)d_in[0];
    const float* dirs   = (const float*)d_in[1];
    const float* table  = (const float*)d_in[2];
    const float* fw1 = (const float*)d_in[3];
    const float* fb1 = (const float*)d_in[4];
    const float* fw2 = (const float*)d_in[5];
    const float* fb2 = (const float*)d_in[6];
    const float* fw3 = (const float*)d_in[7];
    const float* fb3 = (const float*)d_in[8];
    const float* rw1 = (const float*)d_in[9];
    const float* rb1 = (const float*)d_in[10];
    const float* rw2 = (const float*)d_in[11];
    const float* rb2 = (const float*)d_in[12];
    const float* rw3 = (const float*)d_in[13];
    const float* rb3 = (const float*)d_in[14];
    const float* rw4 = (const float*)d_in[15];
    const float* rb4 = (const float*)d_in[16];

    const int N = in_sizes[0] / 3;
    const int table_floats = in_sizes[2];
    const int entries = table_floats / 2;

    // ws layout
    size_t pos = 0;
    auto take = [&](size_t bytes) { size_t p = pos; pos = (pos + bytes + 255) & ~(size_t)255; return p; };
    const size_t o_tableQ = take((size_t)entries * 2);      // fp8 x2 per entry
    const size_t o_emb    = take((size_t)N * 64);
    const size_t o_cS     = take((size_t)N * 16);
    const size_t o_dS     = take((size_t)N * 16);
    const size_t o_hist   = take((size_t)NBINS * 4);
    const size_t o_cursor = take((size_t)NBINS * 4);
    const size_t o_bsum   = take(256 * 4);
    const size_t o_frag   = take((size_t)FRAG_TOTAL * 2);
    const size_t need_full = pos;

    char* ws = (char*)d_ws;

    if (ws_size >= need_full) {
        unsigned short* tableQ = (unsigned short*)(ws + o_tableQ);
        uint4*     embws  = (uint4*)(ws + o_emb);
        float4*    cS     = (float4*)(ws + o_cS);
        float4*    dS     = (float4*)(ws + o_dS);
        unsigned*  hist   = (unsigned*)(ws + o_hist);
        unsigned*  cursor = (unsigned*)(ws + o_cursor);
        unsigned*  bsum   = (unsigned*)(ws + o_bsum);
        _Float16*  frag   = (_Float16*)(ws + o_frag);

        hipLaunchKernelGGL(cvt_table_fp8, dim3(2048), dim3(256), 0, stream,
                           (const float4*)table, (unsigned*)tableQ, table_floats / 4);
        hipLaunchKernelGGL(prep_frags, dim3(FRAG_TOTAL / 256), dim3(256), 0, stream,
                           fw1, fw2, fw3, rw1, rw2, rw3, rw4, frag);
        hipMemsetAsync(hist, 0, (size_t)NBINS * 4, stream);
        hipLaunchKernelGGL(hist_build, dim3((N + 255) / 256), dim3(256), 0, stream,
                           coords, hist, N);
        hipLaunchKernelGGL(scan1, dim3(NBINS / 1024), dim3(256), 0, stream, hist, bsum);
        hipLaunchKernelGGL(scan2, dim3(1), dim3(256), 0, stream, bsum);
        hipLaunchKernelGGL(scan3, dim3(NBINS / 256), dim3(256), 0, stream, hist, bsum, cursor);
        hipLaunchKernelGGL(scatter_pts, dim3((N + 255) / 256), dim3(256), 0, stream,
                           coords, dirs, cursor, cS, dS, N);
        hipLaunchKernelGGL(ngp_encode, dim3((N + EBLK - 1) / EBLK), dim3(EBLK), 0, stream,
                           cS, tableQ, embws, N);
        hipLaunchKernelGGL(ngp_mlp_mfma, dim3((N + 63) / 64), dim3(256), 0, stream,
                           (const _Float16*)embws, dS, frag,
                           fb1, fb2, fb3, rb1, rb2, rb3, rb4,
                           (float*)d_out, N);
    } else {
        hipLaunchKernelGGL(ngp_fused_f32, dim3((N + BLK - 1) / BLK), dim3(BLK), 0, stream,
                           coords, dirs, table,
                           fw1, fb1, fw2, fb2, fw3, fb3,
                           rw1, rb1, rw2, rb2, rw3, rb3, rw4, rb4,
                           (float*)d_out, N);
    }
}

// Round 7
// 909.535 us; speedup vs baseline: 2.8543x; 1.0164x over previous
//
#include <hip/hip_runtime.h>
#include <hip/hip_fp16.h>
#include <math.h>

#define BLK 128          // fused-fallback block
#define EBLK 256         // encode / utility block
#define NBINS (1 << 18)  // 6 bits per axis, Morton sort bins
#define Q_SCALE 65536.0f
#define Q_DESCALE 0x1p-16f

typedef __attribute__((ext_vector_type(8))) _Float16 half8;
typedef __attribute__((ext_vector_type(4))) float f32x4;
typedef __attribute__((ext_vector_type(2))) float f32x2;

// frag offsets in f16 elements: L1,L2,L3,R1,R2,R3,R4
#define FO_L1 0
#define FO_L2 2048
#define FO_L3 6144
#define FO_R1 7168
#define FO_R2 9216
#define FO_R3 13312
#define FO_R4 17408
#define FRAG_TOTAL 18432

// ---- new fp8 table layout ----
// levels 0-7 row-major at OFF[l] (same as source), end 3763373
// hashed 12-15 at HOFF, Morton-block levels 8-11 at MOFF (64^3 tiles)
#define HOFF0 3764224
#define MOFF0 5861376
#define MOFF1 12939264
#define MOFF2 20017152
#define MOFF3 36794368
#define TABQ_ENTRIES 53571584
#define PAIR_LO 1881687
#define PAIR_H  1048576
#define MTOT 47710208

// ---------------- Morton helpers ----------------
__device__ __forceinline__ unsigned mexp(unsigned v) {
    v &= 0x3FF;
    v = (v | (v << 16)) & 0x030000FF;
    v = (v | (v << 8))  & 0x0300F00F;
    v = (v | (v << 4))  & 0x030C30C3;
    v = (v | (v << 2))  & 0x09249249;
    return v;
}
__device__ __forceinline__ unsigned mcomp(unsigned v) {
    v &= 0x09249249u;
    v = (v | (v >> 2)) & 0x030C30C3u;
    v = (v | (v >> 4)) & 0x0300F00Fu;
    v = (v | (v >> 8)) & 0x030000FFu;
    v = (v | (v >> 16)) & 0x3FFu;
    return v;
}
__device__ __forceinline__ unsigned morton_key(float x, float y, float z) {
    int bx = (int)(x * 64.f); bx = bx < 0 ? 0 : (bx > 63 ? 63 : bx);
    int by = (int)(y * 64.f); by = by < 0 ? 0 : (by > 63 ? 63 : by);
    int bz = (int)(z * 64.f); bz = bz < 0 ? 0 : (bz > 63 ? 63 : bz);
    return (mexp((unsigned)bx) << 2) | (mexp((unsigned)by) << 1) | mexp((unsigned)bz);
}

// ---------------- table conversion kernels ----------------
__device__ __forceinline__ unsigned pk_fp8(float a, float b) {
    const int lo = __builtin_amdgcn_cvt_pk_fp8_f32(a * Q_SCALE, b * Q_SCALE, 0, false);
    return (unsigned)lo & 0xFFFFu;
}

// dense levels 0-7: identity copy, pairwise
__global__ __launch_bounds__(256) void cvt_lo(const float4* __restrict__ src,
                                              unsigned* __restrict__ dst)
{
    const int i = blockIdx.x * 256 + threadIdx.x;
    if (i >= PAIR_LO) return;
    const float4 v = src[i];
    dst[i] = pk_fp8(v.x, v.y) | (pk_fp8(v.z, v.w) << 16);
}

// hashed levels 12-15
__global__ __launch_bounds__(256) void cvt_hash(const float4* __restrict__ src,
                                                unsigned* __restrict__ dst)
{
    const int i = blockIdx.x * 256 + threadIdx.x;
    if (i >= PAIR_H) return;
    const float4 v = src[17294596 + i];            // OFF[12]/2 + i
    dst[HOFF0 / 2 + i] = pk_fp8(v.x, v.y) | (pk_fp8(v.z, v.w) << 16);
}

// Morton-block levels 8-11: thread per dest entry
__global__ __launch_bounds__(256) void cvt_morton(const float* __restrict__ srcF,
                                                  unsigned short* __restrict__ dstQ)
{
    const unsigned e = blockIdx.x * 256 + threadIdx.x;
    if (e >= MTOT) return;
    int j, cnt; unsigned base, moff;
    if (e < 14155776u) {
        cnt = 3;
        if (e < 7077888u) { j = 0; base = 0u;        moff = MOFF0; }
        else              { j = 1; base = 7077888u;  moff = MOFF1; }
    } else {
        cnt = 4;
        if (e < 30932992u){ j = 2; base = 14155776u; moff = MOFF2; }
        else              { j = 3; base = 30932992u; moff = MOFF3; }
    }
    const unsigned within = e - base;
    const unsigned blk = within >> 18, lo = within & 0x3FFFFu;
    unsigned bx, by, bz;
    if (cnt == 3) { bx = blk % 3u; const unsigned t = blk / 3u; by = t % 3u; bz = t / 3u; }
    else          { bx = blk & 3u; by = (blk >> 2) & 3u; bz = blk >> 4; }
    const unsigned x = bx * 64u + mcomp(lo);
    const unsigned y = by * 64u + mcomp(lo >> 1);
    const unsigned z = bz * 64u + mcomp(lo >> 2);

    constexpr unsigned RES1[4] = {141u, 169u, 204u, 245u};
    constexpr unsigned SOFF[4] = {3763373u, 6566594u, 11393403u, 19883067u};
    const unsigned r1 = RES1[j];
    unsigned q = 0;
    if (x < r1 && y < r1 && z < r1) {
        const size_t se = (size_t)SOFF[j] + x + (size_t)y * r1 + (size_t)z * r1 * r1;
        const float2 v = *reinterpret_cast<const float2*>(srcF + 2 * se);
        q = pk_fp8(v.x, v.y);
    }
    dstQ[(size_t)moff + within] = (unsigned short)q;
}

// ---------------- weight fragment packing ----------------
__global__ __launch_bounds__(256) void prep_frags(
    const float* __restrict__ fw1, const float* __restrict__ fw2, const float* __restrict__ fw3,
    const float* __restrict__ rw1, const float* __restrict__ rw2, const float* __restrict__ rw3,
    const float* __restrict__ rw4, _Float16* __restrict__ frag)
{
    const int gid = blockIdx.x * 256 + threadIdx.x;
    if (gid >= FRAG_TOTAL) return;
    constexpr int offs[8] = {FO_L1, FO_L2, FO_L3, FO_R1, FO_R2, FO_R3, FO_R4, FRAG_TOTAL};
    constexpr int Ks[7]   = {32, 64, 64, 31, 64, 64, 64};
    constexpr int NO[7]   = {64, 64, 16, 64, 64, 64, 3};
    constexpr int NKs[7]  = {1, 2, 2, 1, 2, 2, 2};
    int layer = 0;
    #pragma unroll
    for (int i = 1; i < 7; ++i) if (gid >= offs[i]) layer = i;
    const float* W = fw1;
    if (layer == 1) W = fw2; else if (layer == 2) W = fw3;
    else if (layer == 3) W = rw1; else if (layer == 4) W = rw2;
    else if (layer == 5) W = rw3; else if (layer == 6) W = rw4;

    const int e = gid - offs[layer];
    const int nk = NKs[layer];
    const int blk = e >> 9, within = e & 511;
    const int t = blk / nk, ks = blk - t * nk;
    const int lane = within >> 3, i = within & 7;
    const int k = ks * 32 + (lane >> 4) * 8 + i;
    // 64-wide layers: col c of tile t holds output feature 4*c + t (paired-store remap)
    const int col = (NO[layer] == 64) ? ((lane & 15) * 4 + t) : (t * 16 + (lane & 15));
    float v = 0.f;
    if (k < Ks[layer] && col < NO[layer]) v = W[k * NO[layer] + col];
    frag[gid] = (_Float16)v;
}

// ---------------- sort: histogram ----------------
__global__ __launch_bounds__(256) void hist_build(const float* __restrict__ coords,
                                                  unsigned* __restrict__ hist, int N)
{
    const int i = blockIdx.x * 256 + threadIdx.x;
    if (i >= N) return;
    const unsigned key = morton_key(coords[3*i+0], coords[3*i+1], coords[3*i+2]);
    atomicAdd(&hist[key], 1u);
}

// ---------------- sort: hierarchical exclusive scan ----------------
__global__ __launch_bounds__(256) void scan1(unsigned* __restrict__ hist, unsigned* __restrict__ bsum)
{
    __shared__ unsigned sa[256], sb[256];
    const int t = threadIdx.x;
    const unsigned base = blockIdx.x * 1024u + (unsigned)t * 4u;
    const unsigned v0 = hist[base+0], v1 = hist[base+1], v2 = hist[base+2], v3 = hist[base+3];
    const unsigned sum = v0 + v1 + v2 + v3;
    sa[t] = sum; __syncthreads();
    unsigned* src = sa; unsigned* dst = sb;
    for (int off = 1; off < 256; off <<= 1) {
        dst[t] = src[t] + (t >= off ? src[t - off] : 0u);
        __syncthreads();
        unsigned* tmp = src; src = dst; dst = tmp;
    }
    const unsigned incl = src[t];
    unsigned run = incl - sum;
    hist[base+0] = run; run += v0;
    hist[base+1] = run; run += v1;
    hist[base+2] = run; run += v2;
    hist[base+3] = run;
    if (t == 255) bsum[blockIdx.x] = incl;
}

__global__ __launch_bounds__(256) void scan2(unsigned* __restrict__ bsum)
{
    __shared__ unsigned sa[256], sb[256];
    const int t = threadIdx.x;
    const unsigned v = bsum[t];
    sa[t] = v; __syncthreads();
    unsigned* src = sa; unsigned* dst = sb;
    for (int off = 1; off < 256; off <<= 1) {
        dst[t] = src[t] + (t >= off ? src[t - off] : 0u);
        __syncthreads();
        unsigned* tmp = src; src = dst; dst = tmp;
    }
    bsum[t] = src[t] - v;
}

__global__ __launch_bounds__(256) void scan3(const unsigned* __restrict__ hist,
                                             const unsigned* __restrict__ bsum,
                                             unsigned* __restrict__ cursor)
{
    const int i = blockIdx.x * 256 + threadIdx.x;
    cursor[i] = hist[i] + bsum[i >> 10];
}

// ---------------- sort: scatter points into bins ----------------
__global__ __launch_bounds__(256) void scatter_pts(const float* __restrict__ coords,
                                                   const float* __restrict__ dirs,
                                                   unsigned* __restrict__ cursor,
                                                   float4* __restrict__ cS,
                                                   float4* __restrict__ dS, int N)
{
    const int i = blockIdx.x * 256 + threadIdx.x;
    if (i >= N) return;
    const float x = coords[3*i+0], y = coords[3*i+1], z = coords[3*i+2];
    const unsigned key = morton_key(x, y, z);
    const unsigned slot = atomicAdd(&cursor[key], 1u);
    cS[slot] = make_float4(x, y, z, __uint_as_float((unsigned)i));
    dS[slot] = make_float4(dirs[3*i+0], dirs[3*i+1], dirs[3*i+2], __uint_as_float((unsigned)i));
}

// ---------------- encode kernel ----------------
__global__ __launch_bounds__(EBLK, 8) void ngp_encode(
    const float4* __restrict__ cS,
    const unsigned short* __restrict__ tableQ,
    uint4* __restrict__ emb_out, int N)
{
    // bijective XCD-contiguous remap of blockIdx (8 XCDs)
    const unsigned nwg = gridDim.x;
    const unsigned bid = blockIdx.x;
    const unsigned qn = nwg >> 3, rn = nwg & 7;
    const unsigned xc = bid & 7, ib = bid >> 3;
    const unsigned nb = (xc < rn ? xc * (qn + 1) : rn * (qn + 1) + (xc - rn) * qn) + ib;

    const int gi = (int)(nb * EBLK + threadIdx.x);
    if (gi >= N) return;

    const float4 cp = cS[gi];
    const float x = cp.x, y = cp.y, z = cp.z;

    float emb[32];

    // ---- dense row-major levels 0-7 ----
    {
        constexpr int RES[8] = {32,38,46,55,67,80,97,116};
        constexpr int OFF[8] = {0,35937,95256,199079,374695,689127,1220568,2161760};
        #pragma unroll
        for (int l = 0; l < 8; ++l) {
            const int res = RES[l];
            const float xl = x * (float)res, yl = y * (float)res, zl = z * (float)res;
            int cx = (int)floorf(xl); cx = cx < 0 ? 0 : (cx > res-1 ? res-1 : cx);
            int cy = (int)floorf(yl); cy = cy < 0 ? 0 : (cy > res-1 ? res-1 : cy);
            int cz = (int)floorf(zl); cz = cz < 0 ? 0 : (cz > res-1 ? res-1 : cz);
            const float wx = xl - (float)cx, wy = yl - (float)cy, wz = zl - (float)cz;
            unsigned qv[8];
            #pragma unroll
            for (int c = 0; c < 8; ++c) {
                const int dx = (c >> 2) & 1, dy = (c >> 1) & 1, dz = c & 1;
                const int idx = (cx+dx) + (cy+dy)*(res+1) + (cz+dz)*(res+1)*(res+1);
                qv[c] = tableQ[OFF[l] + idx];
            }
            float e0 = 0.f, e1 = 0.f;
            #pragma unroll
            for (int c = 0; c < 8; ++c) {
                const int dx = (c >> 2) & 1, dy = (c >> 1) & 1, dz = c & 1;
                const float w = (dx ? wx : 1.f-wx)*(dy ? wy : 1.f-wy)*(dz ? wz : 1.f-wz);
                const f32x2 vf = __builtin_amdgcn_cvt_pk_f32_fp8((int)qv[c], false);
                e0 = fmaf(vf.x, w, e0); e1 = fmaf(vf.y, w, e1);
            }
            emb[2*l+0] = e0 * Q_DESCALE; emb[2*l+1] = e1 * Q_DESCALE;
        }
    }

    // ---- Morton-block dense levels 8-11 ----
    {
        constexpr int RESM[4] = {140,168,203,244};
        constexpr int CNTM[4] = {3,3,4,4};
        constexpr unsigned MOFF[4] = {MOFF0, MOFF1, MOFF2, MOFF3};
        #pragma unroll
        for (int j = 0; j < 4; ++j) {
            const int res = RESM[j];
            const int cnt = CNTM[j];
            const float xl = x * (float)res, yl = y * (float)res, zl = z * (float)res;
            int cx = (int)floorf(xl); cx = cx < 0 ? 0 : (cx > res-1 ? res-1 : cx);
            int cy = (int)floorf(yl); cy = cy < 0 ? 0 : (cy > res-1 ? res-1 : cy);
            int cz = (int)floorf(zl); cz = cz < 0 ? 0 : (cz > res-1 ? res-1 : cz);
            const float wx = xl - (float)cx, wy = yl - (float)cy, wz = zl - (float)cz;

            const int bx0 = cx >> 6, bx1 = (cx+1) >> 6;
            const int by0 = cy >> 6, by1 = (cy+1) >> 6;
            const int bz0 = cz >> 6, bz1 = (cz+1) >> 6;
            const unsigned mx0 = mexp(cx & 63),     mx1 = mexp((cx+1) & 63);
            const unsigned my0 = mexp(cy & 63) << 1, my1 = mexp((cy+1) & 63) << 1;
            const unsigned mz0 = mexp(cz & 63) << 2, mz1 = mexp((cz+1) & 63) << 2;

            unsigned qv[8];
            #pragma unroll
            for (int c = 0; c < 8; ++c) {
                const int dx = (c >> 2) & 1, dy = (c >> 1) & 1, dz = c & 1;
                const int bx = dx ? bx1 : bx0, by = dy ? by1 : by0, bz = dz ? bz1 : bz0;
                const unsigned mm = (dx ? mx1 : mx0) | (dy ? my1 : my0) | (dz ? mz1 : mz0);
                const unsigned blk = (unsigned)((bz * cnt + by) * cnt + bx);
                qv[c] = tableQ[(size_t)MOFF[j] + ((blk << 18) | mm)];
            }
            float e0 = 0.f, e1 = 0.f;
            #pragma unroll
            for (int c = 0; c < 8; ++c) {
                const int dx = (c >> 2) & 1, dy = (c >> 1) & 1, dz = c & 1;
                const float w = (dx ? wx : 1.f-wx)*(dy ? wy : 1.f-wy)*(dz ? wz : 1.f-wz);
                const f32x2 vf = __builtin_amdgcn_cvt_pk_f32_fp8((int)qv[c], false);
                e0 = fmaf(vf.x, w, e0); e1 = fmaf(vf.y, w, e1);
            }
            emb[16+2*j+0] = e0 * Q_DESCALE; emb[16+2*j+1] = e1 * Q_DESCALE;
        }
    }

    // ---- hashed levels 12-15 ----
    {
        constexpr int RESH[4] = {294,353,425,512};
        constexpr unsigned HOFF[4] = {HOFF0, HOFF0+524288, HOFF0+1048576, HOFF0+1572864};
        constexpr unsigned NMASK = (1u << 19) - 1u;
        #pragma unroll
        for (int j = 0; j < 4; ++j) {
            const int res = RESH[j];
            const float xl = x * (float)res, yl = y * (float)res, zl = z * (float)res;
            int cx = (int)floorf(xl); cx = cx < 0 ? 0 : (cx > res-1 ? res-1 : cx);
            int cy = (int)floorf(yl); cy = cy < 0 ? 0 : (cy > res-1 ? res-1 : cy);
            int cz = (int)floorf(zl); cz = cz < 0 ? 0 : (cz > res-1 ? res-1 : cz);
            const float wx = xl - (float)cx, wy = yl - (float)cy, wz = zl - (float)cz;
            unsigned qv[8];
            #pragma unroll
            for (int c = 0; c < 8; ++c) {
                const int dx = (c >> 2) & 1, dy = (c >> 1) & 1, dz = c & 1;
                const unsigned hh = (unsigned)(cx+dx) ^ ((unsigned)(cy+dy) * 2654435761u)
                                  ^ ((unsigned)(cz+dz) * 805459861u);
                qv[c] = tableQ[HOFF[j] + (hh & NMASK)];
            }
            float e0 = 0.f, e1 = 0.f;
            #pragma unroll
            for (int c = 0; c < 8; ++c) {
                const int dx = (c >> 2) & 1, dy = (c >> 1) & 1, dz = c & 1;
                const float w = (dx ? wx : 1.f-wx)*(dy ? wy : 1.f-wy)*(dz ? wz : 1.f-wz);
                const f32x2 vf = __builtin_amdgcn_cvt_pk_f32_fp8((int)qv[c], false);
                e0 = fmaf(vf.x, w, e0); e1 = fmaf(vf.y, w, e1);
            }
            emb[24+2*j+0] = e0 * Q_DESCALE; emb[24+2*j+1] = e1 * Q_DESCALE;
        }
    }

    unsigned packed[16];
    #pragma unroll
    for (int i = 0; i < 16; ++i) {
        const __half2 h = __floats2half2_rn(emb[2*i+0], emb[2*i+1]);
        packed[i] = *reinterpret_cast<const unsigned*>(&h);
    }
    uint4* dst = emb_out + (size_t)gi * 4;
    #pragma unroll
    for (int k = 0; k < 4; ++k)
        dst[k] = make_uint4(packed[4*k+0], packed[4*k+1], packed[4*k+2], packed[4*k+3]);
}

// ================= MFMA MLP =================
__device__ __forceinline__ half8 ldfrag(const _Float16* __restrict__ frags, int off, int l) {
    return *reinterpret_cast<const half8*>(frags + off + l * 8);
}
__device__ __forceinline__ int swz(int f, int p) {
    return ((((f >> 3) + p) & 7) << 3) | (f & 7);
}
__device__ __forceinline__ half8 loadA(const _Float16* T, int p, int kb) {
    return *reinterpret_cast<const half8*>(T + p * 64 + ((((kb >> 3) + p) & 7) << 3));
}
// paired store: acc[t][r] holds output feature 4*p16+t for point g*4+r
template<bool RELU>
__device__ __forceinline__ void storePair(_Float16* T, const f32x4 (&acc)[4], int p16, int g) {
    #pragma unroll
    for (int r = 0; r < 4; ++r) {
        const int p = g * 4 + r;
        float v0 = acc[0][r], v1 = acc[1][r], v2 = acc[2][r], v3 = acc[3][r];
        if (RELU) { v0 = fmaxf(v0,0.f); v1 = fmaxf(v1,0.f); v2 = fmaxf(v2,0.f); v3 = fmaxf(v3,0.f); }
        const __half2 h01 = __floats2half2_rn(v0, v1);
        const __half2 h23 = __floats2half2_rn(v2, v3);
        const int blkb = ((p16 >> 1) + p) & 7;
        uint2* dst = reinterpret_cast<uint2*>(T + p * 64 + blkb * 8 + 4 * (p16 & 1));
        *dst = make_uint2(*reinterpret_cast<const unsigned*>(&h01),
                          *reinterpret_cast<const unsigned*>(&h23));
    }
}
__device__ __forceinline__ void pe_fill(_Float16* T, int p16, int g, float dx, float dy, float dz) {
    float pv0, pv1, pv2, pv3;
    if (g == 0)      { pv0 = dx;             pv1 = dy;         pv2 = dz;             pv3 = __sinf(dx); }
    else if (g == 1) { pv0 = __sinf(2.f*dx); pv1 = __sinf(dy); pv2 = __sinf(2.f*dy); pv3 = __sinf(dz); }
    else if (g == 2) { pv0 = __sinf(2.f*dz); pv1 = __cosf(dx); pv2 = __cosf(2.f*dx); pv3 = __cosf(dy); }
    else             { pv0 = __cosf(2.f*dy); pv1 = __cosf(dz); pv2 = __cosf(2.f*dz); pv3 = 0.f; }
    const float pv[4] = {pv0, pv1, pv2, pv3};
    #pragma unroll
    for (int j2 = 0; j2 < 4; ++j2) {
        const int f = 16 + g * 4 + j2;
        T[p16 * 64 + swz(f, p16)] = (_Float16)pv[j2];
    }
}
#define MFMA16(a, b, c) __builtin_amdgcn_mfma_f32_16x16x32_f16((a), (b), (c), 0, 0, 0)

__global__ __launch_bounds__(256) void ngp_mlp_mfma(
    const _Float16* __restrict__ embws,      // [N][32] f16
    const float4* __restrict__ dS,
    const _Float16* __restrict__ frags,
    const float* __restrict__ fb1, const float* __restrict__ fb2, const float* __restrict__ fb3,
    const float* __restrict__ rb1, const float* __restrict__ rb2, const float* __restrict__ rb3,
    const float* __restrict__ rb4,
    float* __restrict__ out, int N)
{
    __shared__ _Float16 tbuf[4][2][16 * 64];
    __shared__ float obuf[4][2][64];
    const int tid = threadIdx.x;
    const int wv = tid >> 6, l = tid & 63;
    const int p16 = l & 15, g = l >> 4;
    const int wbase = (blockIdx.x * 4 + wv) * 32;
    _Float16* T0 = tbuf[wv][0];
    _Float16* T1 = tbuf[wv][1];
    float* O0 = obuf[wv][0];
    float* O1 = obuf[wv][1];

    int pi0 = wbase + p16;      if (pi0 >= N) pi0 = N - 1;
    int pi1 = wbase + 16 + p16; if (pi1 >= N) pi1 = N - 1;
    const float4 d0 = dS[pi0];
    const float4 d1 = dS[pi1];

    f32x4 ac0[4], ac1[4];
    half8 x00, x01, x10, x11;

    // ---- L1 (K=32): A straight from packed emb ----
    {
        const half8 a0 = *reinterpret_cast<const half8*>(embws + (size_t)pi0 * 32 + g * 8);
        const half8 a1 = *reinterpret_cast<const half8*>(embws + (size_t)pi1 * 32 + g * 8);
        __builtin_amdgcn_s_setprio(1);
        #pragma unroll
        for (int t = 0; t < 4; ++t) {
            const float b = fb1[(p16 << 2) + t];
            const half8 w = ldfrag(frags, FO_L1 + t * 512, l);
            f32x4 c = {b, b, b, b};
            ac0[t] = MFMA16(a0, w, c);
            ac1[t] = MFMA16(a1, w, c);
        }
        __builtin_amdgcn_s_setprio(0);
    }
    storePair<true>(T0, ac0, p16, g);
    storePair<true>(T1, ac1, p16, g);
    x00 = loadA(T0, p16, g*8); x01 = loadA(T0, p16, 32 + g*8);
    x10 = loadA(T1, p16, g*8); x11 = loadA(T1, p16, 32 + g*8);

    // ---- L2 (K=64) ----
    __builtin_amdgcn_s_setprio(1);
    #pragma unroll
    for (int t = 0; t < 4; ++t) {
        const float b = fb2[(p16 << 2) + t];
        const half8 w0 = ldfrag(frags, FO_L2 + (2*t+0) * 512, l);
        const half8 w1 = ldfrag(frags, FO_L2 + (2*t+1) * 512, l);
        f32x4 c0 = {b, b, b, b}, c1 = {b, b, b, b};
        c0 = MFMA16(x00, w0, c0); ac0[t] = MFMA16(x01, w1, c0);
        c1 = MFMA16(x10, w0, c1); ac1[t] = MFMA16(x11, w1, c1);
    }
    __builtin_amdgcn_s_setprio(0);
    storePair<true>(T0, ac0, p16, g);
    storePair<true>(T1, ac1, p16, g);
    x00 = loadA(T0, p16, g*8); x01 = loadA(T0, p16, 32 + g*8);
    x10 = loadA(T1, p16, g*8); x11 = loadA(T1, p16, 32 + g*8);

    // ---- L3 (feat, 16 cols, natural mapping) ----
    {
        const float b = fb3[p16];
        const half8 wa = ldfrag(frags, FO_L3 + 0, l);
        const half8 wb = ldfrag(frags, FO_L3 + 512, l);
        f32x4 c0 = {b, b, b, b}, c1 = {b, b, b, b};
        __builtin_amdgcn_s_setprio(1);
        c0 = MFMA16(x00, wa, c0); c0 = MFMA16(x01, wb, c0);
        c1 = MFMA16(x10, wa, c1); c1 = MFMA16(x11, wb, c1);
        __builtin_amdgcn_s_setprio(0);
        if (p16 == 0) {
            #pragma unroll
            for (int r = 0; r < 4; ++r) {
                O0[(g*4+r)*4 + 3] = __expf(c0[r]);
                O1[(g*4+r)*4 + 3] = __expf(c1[r]);
            }
        }
        #pragma unroll
        for (int r = 0; r < 4; ++r) {
            const int p = g*4 + r;
            T0[p*64 + swz(p16, p)] = (_Float16)c0[r];
            T1[p*64 + swz(p16, p)] = (_Float16)c1[r];
        }
    }

    // ---- PE fill: features 16..31 ----
    pe_fill(T0, p16, g, d0.x, d0.y, d0.z);
    pe_fill(T1, p16, g, d1.x, d1.y, d1.z);
    const half8 ar0 = loadA(T0, p16, g*8);
    const half8 ar1 = loadA(T1, p16, g*8);

    // ---- R1 (K=32) ----
    __builtin_amdgcn_s_setprio(1);
    #pragma unroll
    for (int t = 0; t < 4; ++t) {
        const float b = rb1[(p16 << 2) + t];
        const half8 w = ldfrag(frags, FO_R1 + t * 512, l);
        f32x4 c = {b, b, b, b};
        ac0[t] = MFMA16(ar0, w, c);
        ac1[t] = MFMA16(ar1, w, c);
    }
    __builtin_amdgcn_s_setprio(0);
    storePair<true>(T0, ac0, p16, g);
    storePair<true>(T1, ac1, p16, g);
    x00 = loadA(T0, p16, g*8); x01 = loadA(T0, p16, 32 + g*8);
    x10 = loadA(T1, p16, g*8); x11 = loadA(T1, p16, 32 + g*8);

    // ---- R2 (K=64) ----
    __builtin_amdgcn_s_setprio(1);
    #pragma unroll
    for (int t = 0; t < 4; ++t) {
        const float b = rb2[(p16 << 2) + t];
        const half8 w0 = ldfrag(frags, FO_R2 + (2*t+0) * 512, l);
        const half8 w1 = ldfrag(frags, FO_R2 + (2*t+1) * 512, l);
        f32x4 c0 = {b, b, b, b}, c1 = {b, b, b, b};
        c0 = MFMA16(x00, w0, c0); ac0[t] = MFMA16(x01, w1, c0);
        c1 = MFMA16(x10, w0, c1); ac1[t] = MFMA16(x11, w1, c1);
    }
    __builtin_amdgcn_s_setprio(0);
    storePair<true>(T0, ac0, p16, g);
    storePair<true>(T1, ac1, p16, g);
    x00 = loadA(T0, p16, g*8); x01 = loadA(T0, p16, 32 + g*8);
    x10 = loadA(T1, p16, g*8); x11 = loadA(T1, p16, 32 + g*8);

    // ---- R3 (K=64) ----
    __builtin_amdgcn_s_setprio(1);
    #pragma unroll
    for (int t = 0; t < 4; ++t) {
        const float b = rb3[(p16 << 2) + t];
        const half8 w0 = ldfrag(frags, FO_R3 + (2*t+0) * 512, l);
        const half8 w1 = ldfrag(frags, FO_R3 + (2*t+1) * 512, l);
        f32x4 c0 = {b, b, b, b}, c1 = {b, b, b, b};
        c0 = MFMA16(x00, w0, c0); ac0[t] = MFMA16(x01, w1, c0);
        c1 = MFMA16(x10, w0, c1); ac1[t] = MFMA16(x11, w1, c1);
    }
    __builtin_amdgcn_s_setprio(0);
    storePair<true>(T0, ac0, p16, g);
    storePair<true>(T1, ac1, p16, g);
    x00 = loadA(T0, p16, g*8); x01 = loadA(T0, p16, 32 + g*8);
    x10 = loadA(T1, p16, g*8); x11 = loadA(T1, p16, 32 + g*8);

    // ---- R4 (rgb, 3 cols, natural mapping) ----
    {
        const float b = (p16 < 3) ? rb4[p16] : 0.f;
        const half8 wa = ldfrag(frags, FO_R4 + 0, l);
        const half8 wb = ldfrag(frags, FO_R4 + 512, l);
        f32x4 c0 = {b, b, b, b}, c1 = {b, b, b, b};
        __builtin_amdgcn_s_setprio(1);
        c0 = MFMA16(x00, wa, c0); c0 = MFMA16(x01, wb, c0);
        c1 = MFMA16(x10, wa, c1); c1 = MFMA16(x11, wb, c1);
        __builtin_amdgcn_s_setprio(0);
        if (p16 < 3) {
            #pragma unroll
            for (int r = 0; r < 4; ++r) {
                O0[(g*4+r)*4 + p16] = 1.f / (1.f + __expf(-c0[r]));
                O1[(g*4+r)*4 + p16] = 1.f / (1.f + __expf(-c1[r]));
            }
        }
    }

    // ---- scatter out ----
    if (wbase + p16 < N) {
        const unsigned orig = __float_as_uint(d0.w);
        out[(size_t)orig * 4 + g] = O0[p16 * 4 + g];
    }
    if (wbase + 16 + p16 < N) {
        const unsigned orig = __float_as_uint(d1.w);
        out[(size_t)orig * 4 + g] = O1[p16 * 4 + g];
    }
}

// ---------------- fused fallback (small ws, f32 table) ----------------
template<int NIN, int NOUT, bool RELU>
__device__ __forceinline__ void dense_l(const float* __restrict__ W, const float* __restrict__ Bias,
                                        const float* __restrict__ col, float (&out)[NOUT])
{
    #pragma unroll
    for (int j = 0; j < NOUT; ++j) out[j] = Bias[j];
    #pragma unroll 4
    for (int i = 0; i < NIN; ++i) {
        const float a = col[i * BLK];
        const float* Wr = W + i * NOUT;
        #pragma unroll
        for (int j = 0; j < NOUT; ++j) out[j] = fmaf(a, Wr[j], out[j]);
    }
    if (RELU) {
        #pragma unroll
        for (int j = 0; j < NOUT; ++j) out[j] = fmaxf(out[j], 0.f);
    }
}

__device__ __forceinline__ void encode_point_f(float x, float y, float z,
                                               const float* __restrict__ tableF,
                                               float (&emb)[32])
{
    constexpr int RES[16] = {32,38,46,55,67,80,97,116,140,168,203,244,294,353,425,512};
    constexpr int DN [16] = {1,1,1,1,1,1,1,1,1,1,1,1,0,0,0,0};
    constexpr int OFF[16] = {0,35937,95256,199079,374695,689127,1220568,2161760,
                             3763373,6566594,11393403,19883067,34589192,35113480,
                             35637768,36162056};
    constexpr unsigned NMASK = (1u << 19) - 1u;
    #pragma unroll
    for (int l = 0; l < 16; ++l) {
        const int res = RES[l];
        const float xl = x * (float)res, yl = y * (float)res, zl = z * (float)res;
        int cx = (int)floorf(xl); cx = cx < 0 ? 0 : (cx > res-1 ? res-1 : cx);
        int cy = (int)floorf(yl); cy = cy < 0 ? 0 : (cy > res-1 ? res-1 : cy);
        int cz = (int)floorf(zl); cz = cz < 0 ? 0 : (cz > res-1 ? res-1 : cz);
        const float wx = xl - (float)cx, wy = yl - (float)cy, wz = zl - (float)cz;
        float e0 = 0.f, e1 = 0.f;
        #pragma unroll
        for (int c = 0; c < 8; ++c) {
            const int dx = (c >> 2) & 1, dy = (c >> 1) & 1, dz = c & 1;
            int idx;
            if (DN[l]) {
                idx = (cx+dx) + (cy+dy)*(res+1) + (cz+dz)*(res+1)*(res+1);
            } else {
                const unsigned hh = (unsigned)(cx+dx) ^ ((unsigned)(cy+dy)*2654435761u)
                                  ^ ((unsigned)(cz+dz)*805459861u);
                idx = (int)(hh & NMASK);
            }
            const float w = (dx ? wx : 1.f-wx)*(dy ? wy : 1.f-wy)*(dz ? wz : 1.f-wz);
            const float2 v = *reinterpret_cast<const float2*>(tableF + (size_t)2*(size_t)(OFF[l]+idx));
            e0 = fmaf(v.x, w, e0); e1 = fmaf(v.y, w, e1);
        }
        emb[2*l+0] = e0; emb[2*l+1] = e1;
    }
}

__device__ __forceinline__ float4 mlp_lds(float* col, float dx0, float dy0, float dz0,
    const float* __restrict__ fw1, const float* __restrict__ fb1,
    const float* __restrict__ fw2, const float* __restrict__ fb2,
    const float* __restrict__ fw3, const float* __restrict__ fb3,
    const float* __restrict__ rw1, const float* __restrict__ rb1,
    const float* __restrict__ rw2, const float* __restrict__ rb2,
    const float* __restrict__ rw3, const float* __restrict__ rb3,
    const float* __restrict__ rw4, const float* __restrict__ rb4)
{
    float h[64];
    dense_l<32, 64, true>(fw1, fb1, col, h);
    #pragma unroll
    for (int j = 0; j < 64; ++j) col[j * BLK] = h[j];
    dense_l<64, 64, true>(fw2, fb2, col, h);
    #pragma unroll
    for (int j = 0; j < 64; ++j) col[j * BLK] = h[j];
    float feat16[16];
    dense_l<64, 16, false>(fw3, fb3, col, feat16);
    const float sigma = expf(feat16[0]);
    #pragma unroll
    for (int j = 0; j < 16; ++j) col[j * BLK] = feat16[j];
    col[16 * BLK] = dx0; col[17 * BLK] = dy0; col[18 * BLK] = dz0;
    {
        float s, c;
        sincosf(dx0,     &s, &c); col[19 * BLK] = s; col[25 * BLK] = c;
        sincosf(2.f*dx0, &s, &c); col[20 * BLK] = s; col[26 * BLK] = c;
        sincosf(dy0,     &s, &c); col[21 * BLK] = s; col[27 * BLK] = c;
        sincosf(2.f*dy0, &s, &c); col[22 * BLK] = s; col[28 * BLK] = c;
        sincosf(dz0,     &s, &c); col[23 * BLK] = s; col[29 * BLK] = c;
        sincosf(2.f*dz0, &s, &c); col[24 * BLK] = s; col[30 * BLK] = c;
    }
    dense_l<31, 64, true>(rw1, rb1, col, h);
    #pragma unroll
    for (int j = 0; j < 64; ++j) col[j * BLK] = h[j];
    dense_l<64, 64, true>(rw2, rb2, col, h);
    #pragma unroll
    for (int j = 0; j < 64; ++j) col[j * BLK] = h[j];
    dense_l<64, 64, true>(rw3, rb3, col, h);
    #pragma unroll
    for (int j = 0; j < 64; ++j) col[j * BLK] = h[j];
    float o0 = rb4[0], o1 = rb4[1], o2 = rb4[2];
    #pragma unroll 4
    for (int i = 0; i < 64; ++i) {
        const float a = col[i * BLK];
        o0 = fmaf(a, rw4[i*3 + 0], o0);
        o1 = fmaf(a, rw4[i*3 + 1], o1);
        o2 = fmaf(a, rw4[i*3 + 2], o2);
    }
    o0 = 1.f / (1.f + expf(-o0));
    o1 = 1.f / (1.f + expf(-o1));
    o2 = 1.f / (1.f + expf(-o2));
    return make_float4(o0, o1, o2, sigma);
}

__global__ __launch_bounds__(BLK) void ngp_fused_f32(
    const float* __restrict__ coords,
    const float* __restrict__ dirs,
    const float* __restrict__ tableF,
    const float* __restrict__ fw1, const float* __restrict__ fb1,
    const float* __restrict__ fw2, const float* __restrict__ fb2,
    const float* __restrict__ fw3, const float* __restrict__ fb3,
    const float* __restrict__ rw1, const float* __restrict__ rb1,
    const float* __restrict__ rw2, const float* __restrict__ rb2,
    const float* __restrict__ rw3, const float* __restrict__ rb3,
    const float* __restrict__ rw4, const float* __restrict__ rb4,
    float* __restrict__ out, int N)
{
    __shared__ float sbuf[64 * BLK];
    const int tid = threadIdx.x;
    const int gi  = blockIdx.x * BLK + tid;
    if (gi >= N) return;

    float emb[32];
    encode_point_f(coords[3*gi+0], coords[3*gi+1], coords[3*gi+2], tableF, emb);
    float* col = sbuf + tid;
    #pragma unroll
    for (int j = 0; j < 32; ++j) col[j * BLK] = emb[j];

    const float4 ov = mlp_lds(col, dirs[3*gi+0], dirs[3*gi+1], dirs[3*gi+2],
                              fw1, fb1, fw2, fb2, fw3, fb3,
                              rw1, rb1, rw2, rb2, rw3, rb3, rw4, rb4);
    reinterpret_cast<float4*>(out)[gi] = ov;
}

extern "C" void kernel_launch(void* const* d_in, const int* in_sizes, int n_in,
                              void* d_out, int out_size, void* d_ws, size_t ws_size,
                              hipStream_t stream)
{
    const float* coords = (const float*)d_in[0];
    const float* dirs   = (const float*)d_in[1];
    const float* table  = (const float*)d_in[2];
    const float* fw1 = (const float*)d_in[3];
    const float* fb1 = (const float*)d_in[4];
    const float* fw2 = (const float*)d_in[5];
    const float* fb2 = (const float*)d_in[6];
    const float* fw3 = (const float*)d_in[7];
    const float* fb3 = (const float*)d_in[8];
    const float* rw1 = (const float*)d_in[9];
    const float* rb1 = (const float*)d_in[10];
    const float* rw2 = (const float*)d_in[11];
    const float* rb2 = (const float*)d_in[12];
    const float* rw3 = (const float*)d_in[13];
    const float* rb3 = (const float*)d_in[14];
    const float* rw4 = (const float*)d_in[15];
    const float* rb4 = (const float*)d_in[16];

    const int N = in_sizes[0] / 3;

    // ws layout
    size_t pos = 0;
    auto take = [&](size_t bytes) { size_t p = pos; pos = (pos + bytes + 255) & ~(size_t)255; return p; };
    const size_t o_tableQ = take((size_t)TABQ_ENTRIES * 2);
    const size_t o_emb    = take((size_t)N * 64);
    const size_t o_cS     = take((size_t)N * 16);
    const size_t o_dS     = take((size_t)N * 16);
    const size_t o_hist   = take((size_t)NBINS * 4);
    const size_t o_cursor = take((size_t)NBINS * 4);
    const size_t o_bsum   = take(256 * 4);
    const size_t o_frag   = take((size_t)FRAG_TOTAL * 2);
    const size_t need_full = pos;

    char* ws = (char*)d_ws;

    if (ws_size >= need_full) {
        unsigned short* tableQ = (unsigned short*)(ws + o_tableQ);
        uint4*     embws  = (uint4*)(ws + o_emb);
        float4*    cS     = (float4*)(ws + o_cS);
        float4*    dS     = (float4*)(ws + o_dS);
        unsigned*  hist   = (unsigned*)(ws + o_hist);
        unsigned*  cursor = (unsigned*)(ws + o_cursor);
        unsigned*  bsum   = (unsigned*)(ws + o_bsum);
        _Float16*  frag   = (_Float16*)(ws + o_frag);

        hipLaunchKernelGGL(cvt_lo, dim3((PAIR_LO + 255) / 256), dim3(256), 0, stream,
                           (const float4*)table, (unsigned*)tableQ);
        hipLaunchKernelGGL(cvt_hash, dim3(PAIR_H / 256), dim3(256), 0, stream,
                           (const float4*)table, (unsigned*)tableQ);
        hipLaunchKernelGGL(cvt_morton, dim3(MTOT / 256), dim3(256), 0, stream,
                           table, tableQ);
        hipLaunchKernelGGL(prep_frags, dim3(FRAG_TOTAL / 256), dim3(256), 0, stream,
                           fw1, fw2, fw3, rw1, rw2, rw3, rw4, frag);
        hipMemsetAsync(hist, 0, (size_t)NBINS * 4, stream);
        hipLaunchKernelGGL(hist_build, dim3((N + 255) / 256), dim3(256), 0, stream,
                           coords, hist, N);
        hipLaunchKernelGGL(scan1, dim3(NBINS / 1024), dim3(256), 0, stream, hist, bsum);
        hipLaunchKernelGGL(scan2, dim3(1), dim3(256), 0, stream, bsum);
        hipLaunchKernelGGL(scan3, dim3(NBINS / 256), dim3(256), 0, stream, hist, bsum, cursor);
        hipLaunchKernelGGL(scatter_pts, dim3((N + 255) / 256), dim3(256), 0, stream,
                           coords, dirs, cursor, cS, dS, N);
        hipLaunchKernelGGL(ngp_encode, dim3((N + EBLK - 1) / EBLK), dim3(EBLK), 0, stream,
                           cS, tableQ, embws, N);
        hipLaunchKernelGGL(ngp_mlp_mfma, dim3((N + 127) / 128), dim3(256), 0, stream,
                           (const _Float16*)embws, dS, frag,
                           fb1, fb2, fb3, rb1, rb2, rb3, rb4,
                           (float*)d_out, N);
    } else {
        hipLaunchKernelGGL(ngp_fused_f32, dim3((N + BLK - 1) / BLK), dim3(BLK), 0, stream,
                           coords, dirs, table,
                           fw1, fb1, fw2, fb2, fw3, fb3,
                           rw1, rb1, rw2, rb2, rw3, rb3, rw4, rb4,
                           (float*)d_out, N);
    }
}